// Round 9
// baseline (417.539 us; speedup 1.0000x reference)
//
#include <hip/hip_runtime.h>
#include <math.h>

// ---------------------------------------------------------------------------
// Bidirectional Mamba encoder, round 9.
// Round-8 bf16-MFMA GEMMs kept. Scan: NCH 16->32 chunks (TC=36, LP=1152),
// doubling wave count to the 32/CU cap and halving serial depth. sumP
// replaced by per-(chunk,d) sum-of-delta stashed in YT's unread tail rows
// (1056..1151); scan2 rebuilds P = exp(A*sdl) on the fly. sumH (1.05M
// floats) still overlays H1. scan2 write guard keeps the tail rows clean.
// ---------------------------------------------------------------------------

#define L_SEQ 1031
#define LP    1152          // 32 chunks x 36
#define TC    36
#define NCH   32
#define SDROW 1056          // first YT tail row used for sdl stash
#define BATCH 8
#define NVAR  1024
#define SEQQ  512
#define TFEAT 7

#define SZ_H    ((size_t)BATCH * L_SEQ * 128)
#define SZ_XZ   ((size_t)2 * BATCH * L_SEQ * 256)
#define SZ_DT   ((size_t)2 * BATCH * 128 * LP)
#define SZ_BC   ((size_t)2 * BATCH * 16 * LP)
#define OFF_H    ((size_t)0)
#define OFF_H1   (OFF_H + SZ_H)
#define OFF_XZ   (OFF_H1 + SZ_H)
#define OFF_XCT  (OFF_XZ + SZ_XZ)
#define OFF_DLT  (OFF_XCT + SZ_DT)
#define OFF_BMT  (OFF_DLT + SZ_DT)
#define OFF_CMT  (OFF_BMT + SZ_BC)
#define OFF_YT   (OFF_CMT + SZ_BC)
#define SZ_SUM  ((size_t)2 * BATCH * NCH * 128 * 16)   // 1,048,576 <= SZ_H

typedef __bf16 bf16_t;
typedef bf16_t bf16x4 __attribute__((ext_vector_type(4)));
typedef bf16_t bf16x8 __attribute__((ext_vector_type(8)));
typedef float floatx4 __attribute__((ext_vector_type(4)));

#define MFMA16(a, b, c) __builtin_amdgcn_mfma_f32_16x16x32_bf16((a), (b), (c), 0, 0, 0)

__device__ __forceinline__ float silu_f(float x) {
  return x / (1.f + __expf(-x));
}
__device__ __forceinline__ float softplus_f(float x) {
  return (x > 20.f) ? x : log1pf(__expf(x));
}
__device__ __forceinline__ float red8(float x) {
  x += __int_as_float(__builtin_amdgcn_update_dpp(
      0, __float_as_int(x), 0xB1, 0xF, 0xF, true));   // quad_perm [1,0,3,2]
  x += __int_as_float(__builtin_amdgcn_update_dpp(
      0, __float_as_int(x), 0x4E, 0xF, 0xF, true));   // quad_perm [2,3,0,1]
  x += __int_as_float(__builtin_amdgcn_update_dpp(
      0, __float_as_int(x), 0x141, 0xF, 0xF, true));  // row_half_mirror
  return x;
}

// Stage 128xK-chunk of a row-major [N][K] fp32 weight into Wbf (bf16).
#define STAGE_W128(WBUF, SRC, LDK, K0)                                       \
  _Pragma("unroll")                                                          \
  for (int i_ = 0; i_ < 16; i_++) {                                          \
    int e_ = tid + i_ * 256;                                                 \
    int n_ = e_ >> 5, kq_ = e_ & 31;                                         \
    float4 wv_ = *(const float4*)&(SRC)[(size_t)n_ * (LDK) + (K0) + kq_ * 4];\
    bf16x4 bv_ = {(bf16_t)wv_.x, (bf16_t)wv_.y, (bf16_t)wv_.z, (bf16_t)wv_.w};\
    *(bf16x4*)&WBUF[n_][kq_ * 4] = bv_;                                      \
  }

// 16 MFMAs: full K=128 panel for this wave's 16x64 output.
#define MFMA_K128(ABUF, WBUF, ACC)                                           \
  _Pragma("unroll")                                                          \
  for (int kc_ = 0; kc_ < 4; kc_++) {                                        \
    bf16x8 a_ = *(const bf16x8*)&ABUF[arow][kc_ * 32 + q8];                  \
    _Pragma("unroll")                                                        \
    for (int nt_ = 0; nt_ < 4; nt_++) {                                      \
      bf16x8 b_ = *(const bf16x8*)&WBUF[wcol + nt_ * 16 + ln][kc_ * 32 + q8];\
      ACC[nt_] = MFMA16(a_, b_, ACC[nt_]);                                   \
    }                                                                        \
  }

// ---------------------------------------------------------------------------
// k_embed: H[b,v,:] = token(b,v,:) @ emb_w.T + emb_b. K=512 (4 panels).
// grid (33, 8), block 256.   (round-8, proven)
// ---------------------------------------------------------------------------
__global__ __launch_bounds__(256) void k_embed(
    const float* __restrict__ x_enc, const float* __restrict__ x_mark,
    const float* __restrict__ emb_w, const float* __restrict__ emb_b,
    float* __restrict__ H) {
  int b = blockIdx.y;
  int v0 = blockIdx.x * 32;
  int tid = threadIdx.x;
  __shared__ bf16_t Abf[32][136];
  __shared__ bf16_t Wbf[128][136];
  int lane = tid & 63, ln = lane & 15, q = lane >> 4, q8 = q * 8;
  int w = tid >> 6, rw = w & 1, cw = w >> 1;
  int arow = rw * 16 + ln, wcol = cw * 64;
  floatx4 acc[4];
#pragma unroll
  for (int nt = 0; nt < 4; nt++) acc[nt] = (floatx4){0.f, 0.f, 0.f, 0.f};

  for (int c = 0; c < 4; c++) {
    int s0 = c * 128;
#pragma unroll
    for (int i = 0; i < 4; i++) {
      int e = tid + i * 256;
      int s = e >> 3, vq = e & 7;
      int vg = v0 + vq * 4;
      float4 xv;
      if (vg + 3 < NVAR) {
        xv = *(const float4*)&x_enc[((size_t)b * SEQQ + s0 + s) * NVAR + vg];
        if (xv.x == -9999.f) xv.x = -1.f;
        if (xv.y == -9999.f) xv.y = -1.f;
        if (xv.z == -9999.f) xv.z = -1.f;
        if (xv.w == -9999.f) xv.w = -1.f;
      } else {
        float tmp[4];
#pragma unroll
        for (int u = 0; u < 4; u++) {
          int v = vg + u;
          tmp[u] = (v < L_SEQ)
                       ? x_mark[((size_t)b * SEQQ + s0 + s) * TFEAT + (v - NVAR)]
                       : 0.f;
        }
        xv = make_float4(tmp[0], tmp[1], tmp[2], tmp[3]);
      }
      Abf[vq * 4 + 0][s] = (bf16_t)xv.x;
      Abf[vq * 4 + 1][s] = (bf16_t)xv.y;
      Abf[vq * 4 + 2][s] = (bf16_t)xv.z;
      Abf[vq * 4 + 3][s] = (bf16_t)xv.w;
    }
    STAGE_W128(Wbf, emb_w, SEQQ, s0);
    __syncthreads();
    MFMA_K128(Abf, Wbf, acc);
    __syncthreads();
  }
#pragma unroll
  for (int r = 0; r < 4; r++) {
    int v = v0 + rw * 16 + q * 4 + r;
    if (v < L_SEQ) {
      float* dst = &H[((size_t)b * L_SEQ + v) * 128];
#pragma unroll
      for (int nt = 0; nt < 4; nt++) {
        int col = wcol + nt * 16 + ln;
        dst[col] = acc[nt][r] + emb_b[col];
      }
    }
  }
}

// ---------------------------------------------------------------------------
// k_xz  (round-8, proven)
// ---------------------------------------------------------------------------
__global__ __launch_bounds__(256) void k_xz(
    const float* __restrict__ H, const float* __restrict__ ipw,
    float* __restrict__ XZ, int l) {
  int b = blockIdx.y;
  int dir = blockIdx.z >> 1, nh = blockIdx.z & 1;
  int t0 = blockIdx.x * 32;
  int tid = threadIdx.x;
  __shared__ bf16_t Abf[32][136];
  __shared__ bf16_t Wbf[128][136];
  int lane = tid & 63, ln = lane & 15, q = lane >> 4, q8 = q * 8;
  int w = tid >> 6, rw = w & 1, cw = w >> 1;
  int arow = rw * 16 + ln, wcol = cw * 64;
  floatx4 acc[4];
#pragma unroll
  for (int nt = 0; nt < 4; nt++) acc[nt] = (floatx4){0.f, 0.f, 0.f, 0.f};
  const float* wbase = ipw + (size_t)(l * 2 + dir) * 256 * 128 + (size_t)nh * 128 * 128;

#pragma unroll
  for (int i = 0; i < 4; i++) {
    int e = tid + i * 256;
    int tl = e >> 5, kq = e & 31;
    int t = t0 + tl;
    float4 hv = make_float4(0.f, 0.f, 0.f, 0.f);
    if (t < L_SEQ) {
      int st = dir ? (L_SEQ - 1 - t) : t;
      hv = *(const float4*)&H[((size_t)b * L_SEQ + st) * 128 + kq * 4];
    }
    bf16x4 av = {(bf16_t)hv.x, (bf16_t)hv.y, (bf16_t)hv.z, (bf16_t)hv.w};
    *(bf16x4*)&Abf[tl][kq * 4] = av;
  }
  STAGE_W128(Wbf, wbase, 128, 0);
  __syncthreads();
  MFMA_K128(Abf, Wbf, acc);

#pragma unroll
  for (int r = 0; r < 4; r++) {
    int t = t0 + rw * 16 + q * 4 + r;
    if (t < L_SEQ) {
      float* dst = XZ + ((size_t)(dir * BATCH + b) * L_SEQ + t) * 256 + nh * 128;
#pragma unroll
      for (int nt = 0; nt < 4; nt++) dst[wcol + nt * 16 + ln] = acc[nt][r];
    }
  }
}

// ---------------------------------------------------------------------------
// k_mid  (round-5, proven; grid (36,8,2) covers LP=1152)
// ---------------------------------------------------------------------------
__global__ __launch_bounds__(256) void k_mid(
    const float* __restrict__ XZ,
    const float* __restrict__ conv_w, const float* __restrict__ conv_b,
    const float* __restrict__ xpw,
    const float* __restrict__ dpw, const float* __restrict__ dpb,
    float* __restrict__ XCT, float* __restrict__ DLT,
    float* __restrict__ BmT, float* __restrict__ CmT, int l) {
  int b = blockIdx.y, dir = blockIdx.z;
  int t0 = blockIdx.x * 32;
  int tid = threadIdx.x;
  int pg = l * 2 + dir;
  __shared__ float xcs[32][132];
  __shared__ float xpws[40][128];
  __shared__ float dbcs[40][36];
  const float* xz = XZ + (size_t)(dir * BATCH + b) * L_SEQ * 256;

  for (int i = 0; i < 20; i++) {
    int e = tid + i * 256;
    int k = e & 127, j = e >> 7;
    xpws[j][k] = xpw[((size_t)pg * 40 + j) * 128 + k];
  }
  for (int i = 0; i < 16; i++) {
    int e = tid + i * 256;
    int d = e & 127, tl = e >> 7;
    int t = t0 + tl;
    float v = 0.f;
    if (t < L_SEQ) {
      float x1 = xz[(size_t)t * 256 + d];
      float x0 = (t > 0) ? xz[(size_t)(t - 1) * 256 + d] : 0.f;
      float c0 = conv_w[((size_t)pg * 128 + d) * 2 + 0];
      float c1 = conv_w[((size_t)pg * 128 + d) * 2 + 1];
      v = silu_f(x0 * c0 + x1 * c1 + conv_b[(size_t)pg * 128 + d]);
    }
    xcs[tl][d] = v;
  }
  __syncthreads();
  {
    int tl = tid & 31, jg = tid >> 5;
    float acc[5] = {0.f};
    const float4* xrow = (const float4*)&xcs[tl][0];
    for (int kk = 0; kk < 32; kk++) {
      float4 a = xrow[kk];
#pragma unroll
      for (int jj = 0; jj < 5; jj++) {
        float4 w = ((const float4*)&xpws[jg * 5 + jj][0])[kk];
        acc[jj] = fmaf(a.x, w.x, acc[jj]);
        acc[jj] = fmaf(a.y, w.y, acc[jj]);
        acc[jj] = fmaf(a.z, w.z, acc[jj]);
        acc[jj] = fmaf(a.w, w.w, acc[jj]);
      }
    }
#pragma unroll
    for (int jj = 0; jj < 5; jj++) dbcs[jg * 5 + jj][tl] = acc[jj];
  }
  __syncthreads();
  for (int i = 0; i < 4; i++) {
    int e = tid + i * 256;
    int tl = e & 31, r = e >> 5;
    int n = r & 15, isC = r >> 4;
    int t = t0 + tl;
    if (t < LP) {
      float v = dbcs[8 + isC * 16 + n][tl];
      float* dst = isC ? CmT : BmT;
      dst[((size_t)(dir * BATCH + b) * 16 + n) * LP + t] = v;
    }
  }
  {
    int d = tid & 127, th = tid >> 7;
    float dw[8];
#pragma unroll
    for (int k = 0; k < 8; k++) dw[k] = dpw[((size_t)pg * 128 + d) * 8 + k];
    float dbv = dpb[(size_t)pg * 128 + d];
    size_t base = ((size_t)(dir * BATCH + b) * 128 + d) * LP;
    for (int tb = th * 16; tb < th * 16 + 16; tb += 4) {
      int t = t0 + tb;
      if (t < LP) {
        float dv[4], xv[4];
#pragma unroll
        for (int u = 0; u < 4; u++) {
          int tl = tb + u;
          float a = dbv;
#pragma unroll
          for (int k = 0; k < 8; k++) a = fmaf(dbcs[k][tl], dw[k], a);
          dv[u] = softplus_f(a);
          xv[u] = xcs[tl][d];
        }
        *(float4*)(DLT + base + t) = make_float4(dv[0], dv[1], dv[2], dv[3]);
        *(float4*)(XCT + base + t) = make_float4(xv[0], xv[1], xv[2], xv[3]);
      }
    }
  }
}

// ---------------------------------------------------------------------------
// k_scan1: pass 1. TC=36 chunk-local recurrence from h=0; stores h_end
// (sumH, H1 overlay) and sum-of-delta (YT tail rows). grid (16,8,64).
// ---------------------------------------------------------------------------
__global__ __launch_bounds__(64) void k_scan1(
    const float* __restrict__ DLT, const float* __restrict__ XCT,
    const float* __restrict__ BmT,
    const float* __restrict__ A_log,
    float* __restrict__ sumH, float* __restrict__ YT, int l) {
  int z = blockIdx.z;
  int dir = z >> 5, j = z & 31;
  int b = blockIdx.y;
  int lane = threadIdx.x;
  int np = lane & 7, ds = lane >> 3;
  int d = blockIdx.x * 8 + ds;
  int pg = l * 2 + dir;
  int n0 = np * 2;
  int dirb = dir * BATCH + b;
  float A0 = -__expf(A_log[((size_t)pg * 128 + d) * 16 + n0]);
  float A1 = -__expf(A_log[((size_t)pg * 128 + d) * 16 + n0 + 1]);
  size_t bd = ((size_t)dirb * 128 + d) * LP + (size_t)j * TC;
  size_t bn = ((size_t)dirb * 16 + n0) * LP + (size_t)j * TC;
  const float4* dl4 = (const float4*)(DLT + bd);
  const float4* xc4 = (const float4*)(XCT + bd);
  const float4* b04 = (const float4*)(BmT + bn);
  const float4* b14 = (const float4*)(BmT + bn + LP);
  float h0 = 0.f, h1 = 0.f, sdl = 0.f;
  const int NI = TC / 4;   // 9
  float4 cd = dl4[0], cx = xc4[0], cb0 = b04[0], cb1 = b14[0];
#define P1STEP(DL, XC, B0, B1)                       \
  {                                                  \
    float du_ = (DL) * (XC);                         \
    h0 = fmaf(__expf((DL) * A0), h0, du_ * (B0));    \
    h1 = fmaf(__expf((DL) * A1), h1, du_ * (B1));    \
  }
  for (int i = 0; i < NI; i++) {
    float4 nd = cd, nx = cx, nb0 = cb0, nb1 = cb1;
    if (i + 1 < NI) {
      nd = dl4[i + 1]; nx = xc4[i + 1];
      nb0 = b04[i + 1]; nb1 = b14[i + 1];
    }
    P1STEP(cd.x, cx.x, cb0.x, cb1.x);
    P1STEP(cd.y, cx.y, cb0.y, cb1.y);
    P1STEP(cd.z, cx.z, cb0.z, cb1.z);
    P1STEP(cd.w, cx.w, cb0.w, cb1.w);
    sdl += (cd.x + cd.y) + (cd.z + cd.w);
    cd = nd; cx = nx; cb0 = nb0; cb1 = nb1;
  }
#undef P1STEP
  size_t si = (((size_t)dirb * NCH + j) * 128 + d) * 16 + n0;
  *(float2*)&sumH[si] = make_float2(h0, h1);
  if (np == 0) {
    YT[((size_t)dirb * LP + SDROW + j) * 128 + d] = sdl;
  }
}

// ---------------------------------------------------------------------------
// k_scan2: pass 2. Rebuild init via P=exp(A*sdl[jj]) (<=31 iters), re-run
// chunk, DPP-reduce, gate with silu(z), write Y[t][d] (t<SDROW only).
// grid (16, 8, 64), block 64.
// ---------------------------------------------------------------------------
__global__ __launch_bounds__(64) void k_scan2(
    const float* __restrict__ DLT, const float* __restrict__ XCT,
    const float* __restrict__ BmT, const float* __restrict__ CmT,
    const float* __restrict__ XZ,
    const float* __restrict__ A_log, const float* __restrict__ Dpar,
    const float* __restrict__ sumH,
    float* __restrict__ YT, int l) {
  int z = blockIdx.z;
  int dir = z >> 5, j = z & 31;
  int b = blockIdx.y;
  int lane = threadIdx.x;
  int np = lane & 7, ds = lane >> 3;
  int d = blockIdx.x * 8 + ds;
  int pg = l * 2 + dir;
  int n0 = np * 2;
  int dirb = dir * BATCH + b;
  float A0 = -__expf(A_log[((size_t)pg * 128 + d) * 16 + n0]);
  float A1 = -__expf(A_log[((size_t)pg * 128 + d) * 16 + n0 + 1]);
  float Dv = Dpar[(size_t)pg * 128 + d];
  float h0 = 0.f, h1 = 0.f;
  {
    size_t sbase = ((size_t)dirb * NCH) * 2048 + (size_t)d * 16 + n0;
    const float* sdbase = YT + ((size_t)dirb * LP + SDROW) * 128 + d;
    for (int jj = 0; jj < j; jj++) {
      float2 hE = *(const float2*)&sumH[sbase + (size_t)jj * 2048];
      float sdl = sdbase[(size_t)jj * 128];
      h0 = fmaf(__expf(A0 * sdl), h0, hE.x);
      h1 = fmaf(__expf(A1 * sdl), h1, hE.y);
    }
  }
  size_t bd = ((size_t)dirb * 128 + d) * LP + (size_t)j * TC;
  size_t bn = ((size_t)dirb * 16 + n0) * LP + (size_t)j * TC;
  const float4* dl4 = (const float4*)(DLT + bd);
  const float4* xc4 = (const float4*)(XCT + bd);
  const float4* b04 = (const float4*)(BmT + bn);
  const float4* b14 = (const float4*)(BmT + bn + LP);
  const float4* c04 = (const float4*)(CmT + bn);
  const float4* c14 = (const float4*)(CmT + bn + LP);
  const float* zbase = XZ + (size_t)dirb * L_SEQ * 256 + 128 + d
                       + (size_t)j * TC * 256;
  float* ybase = YT + ((size_t)dirb * LP + (size_t)j * TC) * 128 + d;
  const int NI = TC / 4;   // 9
  float4 cd = dl4[0], cx = xc4[0], cb0 = b04[0], cb1 = b14[0];
  float4 cc0 = c04[0], cc1 = c14[0];
  float zc[4], zn[4];
  if (np == 0) {
#pragma unroll
    for (int u = 0; u < 4; u++) zc[u] = zbase[(size_t)u * 256];
  }
#define STEP1(DL, XC, B0, B1, C0, C1, YO)            \
  {                                                  \
    float du_ = (DL) * (XC);                         \
    h0 = fmaf(__expf((DL) * A0), h0, du_ * (B0));    \
    h1 = fmaf(__expf((DL) * A1), h1, du_ * (B1));    \
    float p_ = red8(fmaf(h1, (C1), h0 * (C0)));      \
    (YO) = fmaf(Dv, (XC), p_);                       \
  }
  for (int i = 0; i < NI; i++) {
    float4 nd = cd, nx = cx, nb0 = cb0, nb1 = cb1, nc0 = cc0, nc1 = cc1;
    if (i + 1 < NI) {
      nd = dl4[i + 1]; nx = xc4[i + 1];
      nb0 = b04[i + 1]; nb1 = b14[i + 1];
      nc0 = c04[i + 1]; nc1 = c14[i + 1];
      if (np == 0) {
        int tb = (i + 1) * 4;
#pragma unroll
        for (int u = 0; u < 4; u++) zn[u] = zbase[(size_t)(tb + u) * 256];
      }
    }
    float4 y;
    STEP1(cd.x, cx.x, cb0.x, cb1.x, cc0.x, cc1.x, y.x);
    STEP1(cd.y, cx.y, cb0.y, cb1.y, cc0.y, cc1.y, y.y);
    STEP1(cd.z, cx.z, cb0.z, cb1.z, cc0.z, cc1.z, y.z);
    STEP1(cd.w, cx.w, cb0.w, cb1.w, cc0.w, cc1.w, y.w);
    if (np == 0) {
      int tg = j * TC + i * 4;   // global t of first element
      float yv[4] = {y.x * silu_f(zc[0]), y.y * silu_f(zc[1]),
                     y.z * silu_f(zc[2]), y.w * silu_f(zc[3])};
#pragma unroll
      for (int u = 0; u < 4; u++) {
        if (tg + u < SDROW) ybase[(size_t)(i * 4 + u) * 128] = yv[u];
      }
#pragma unroll
      for (int u = 0; u < 4; u++) zc[u] = zn[u];
    }
    cd = nd; cx = nx; cb0 = nb0; cb1 = nb1; cc0 = nc0; cc1 = nc1;
  }
#undef STEP1
}

// ---------------------------------------------------------------------------
// k_out  (round-8, proven; reads Y[t][d], rows <= 1055 < SDROW)
// ---------------------------------------------------------------------------
__global__ __launch_bounds__(256) void k_out(
    const float* __restrict__ YT, const float* __restrict__ Hin,
    const float* __restrict__ opw,
    const float* __restrict__ n1w, const float* __restrict__ n1b,
    float* __restrict__ H1, int l) {
  int b = blockIdx.y;
  int t0 = blockIdx.x * 32;
  int tid = threadIdx.x;
  __shared__ bf16_t Abf[32][136];
  __shared__ bf16_t Wbf[128][136];
  __shared__ float Ssum[2][32][2];
  int lane = tid & 63, ln = lane & 15, q = lane >> 4, q8 = q * 8;
  int w = tid >> 6, rw = w & 1, cw = w >> 1;
  int arow = rw * 16 + ln, wcol = cw * 64;
  floatx4 acc[4];
#pragma unroll
  for (int nt = 0; nt < 4; nt++) acc[nt] = (floatx4){0.f, 0.f, 0.f, 0.f};

  for (int dirp = 0; dirp < 2; dirp++) {
    const float* ysrc = YT + (size_t)(dirp * BATCH + b) * LP * 128;
#pragma unroll
    for (int i = 0; i < 4; i++) {
      int e = tid + i * 256;
      int tl = e >> 5, dq = e & 31;
      int tg = t0 + tl;
      int srow = dirp ? (L_SEQ - 1 - tg) : tg;
      float4 yv = make_float4(0.f, 0.f, 0.f, 0.f);
      if (srow >= 0) yv = *(const float4*)&ysrc[(size_t)srow * 128 + dq * 4];
      bf16x4 av = {(bf16_t)yv.x, (bf16_t)yv.y, (bf16_t)yv.z, (bf16_t)yv.w};
      *(bf16x4*)&Abf[tl][dq * 4] = av;
    }
    const float* wsrc = opw + (size_t)(l * 2 + dirp) * 128 * 128;
    STAGE_W128(Wbf, wsrc, 128, 0);
    __syncthreads();
    MFMA_K128(Abf, Wbf, acc);
    __syncthreads();
  }
  const float* nw = n1w + l * 128;
  const float* nbv = n1b + l * 128;
  float vres[4][4];
  float s1r[4], s2r[4];
#pragma unroll
  for (int r = 0; r < 4; r++) {
    int t = t0 + rw * 16 + q * 4 + r;
    float s1 = 0.f, s2 = 0.f;
#pragma unroll
    for (int nt = 0; nt < 4; nt++) {
      int col = wcol + nt * 16 + ln;
      float resid = (t < L_SEQ) ? Hin[((size_t)b * L_SEQ + t) * 128 + col] : 0.f;
      float v = acc[nt][r] + resid;
      vres[r][nt] = v;
      s1 += v;
      s2 += v * v;
    }
#pragma unroll
    for (int m = 1; m < 16; m <<= 1) {
      s1 += __shfl_xor(s1, m);
      s2 += __shfl_xor(s2, m);
    }
    s1r[r] = s1; s2r[r] = s2;
  }
  if (ln == 0) {
#pragma unroll
    for (int r = 0; r < 4; r++) {
      Ssum[cw][rw * 16 + q * 4 + r][0] = s1r[r];
      Ssum[cw][rw * 16 + q * 4 + r][1] = s2r[r];
    }
  }
  __syncthreads();
#pragma unroll
  for (int r = 0; r < 4; r++) {
    int row = rw * 16 + q * 4 + r;
    float s1 = s1r[r] + Ssum[cw ^ 1][row][0];
    float s2 = s2r[r] + Ssum[cw ^ 1][row][1];
    float mean = s1 * (1.f / 128.f);
    float rstd = rsqrtf(s2 * (1.f / 128.f) - mean * mean + 1e-5f);
    int t = t0 + row;
    if (t < L_SEQ) {
#pragma unroll
      for (int nt = 0; nt < 4; nt++) {
        int col = wcol + nt * 16 + ln;
        H1[((size_t)b * L_SEQ + t) * 128 + col] =
            (vres[r][nt] - mean) * rstd * nw[col] + nbv[col];
      }
    }
  }
}

// ---------------------------------------------------------------------------
// k_ffn  (round-8, proven)
// ---------------------------------------------------------------------------
__global__ __launch_bounds__(256) void k_ffn(
    const float* __restrict__ H1, const float* __restrict__ w1,
    const float* __restrict__ b1, const float* __restrict__ w2,
    const float* __restrict__ b2, const float* __restrict__ n2w,
    const float* __restrict__ n2b, float* __restrict__ Hout, int l) {
  int b = blockIdx.y;
  int t0 = blockIdx.x * 32;
  int tid = threadIdx.x;
  __shared__ bf16_t Abf[32][136];
  __shared__ bf16_t Wbf[128][136];
  __shared__ bf16_t Ut[32][136];
  __shared__ float Ssum[2][32][2];
  int lane = tid & 63, ln = lane & 15, q = lane >> 4, q8 = q * 8;
  int w = tid >> 6, rw = w & 1, cw = w >> 1;
  int arow = rw * 16 + ln, wcol = cw * 64;
  floatx4 acc[4];
#pragma unroll
  for (int nt = 0; nt < 4; nt++) acc[nt] = (floatx4){0.f, 0.f, 0.f, 0.f};
  const float* w1b = w1 + (size_t)l * 128 * 128;
  const float* w2b = w2 + (size_t)l * 128 * 128;

#pragma unroll
  for (int i = 0; i < 4; i++) {
    int e = tid + i * 256;
    int tl = e >> 5, kq = e & 31;
    int t = t0 + tl;
    float4 hv = make_float4(0.f, 0.f, 0.f, 0.f);
    if (t < L_SEQ)
      hv = *(const float4*)&H1[((size_t)b * L_SEQ + t) * 128 + kq * 4];
    bf16x4 av = {(bf16_t)hv.x, (bf16_t)hv.y, (bf16_t)hv.z, (bf16_t)hv.w};
    *(bf16x4*)&Abf[tl][kq * 4] = av;
  }
  STAGE_W128(Wbf, w1b, 128, 0);
  __syncthreads();
  MFMA_K128(Abf, Wbf, acc);
  __syncthreads();
  {
    float b1v[4];
#pragma unroll
    for (int nt = 0; nt < 4; nt++) b1v[nt] = b1[l * 128 + wcol + nt * 16 + ln];
#pragma unroll
    for (int nt = 0; nt < 4; nt++) {
#pragma unroll
      for (int r = 0; r < 4; r++) {
        Ut[rw * 16 + q * 4 + r][wcol + nt * 16 + ln] =
            (bf16_t)fmaxf(acc[nt][r] + b1v[nt], 0.f);
      }
      acc[nt] = (floatx4){0.f, 0.f, 0.f, 0.f};
    }
  }
  STAGE_W128(Wbf, w2b, 128, 0);
  __syncthreads();
  MFMA_K128(Ut, Wbf, acc);
  const float* nw = n2w + l * 128;
  const float* nbv = n2b + l * 128;
  float vres[4][4];
  float s1r[4], s2r[4];
#pragma unroll
  for (int r = 0; r < 4; r++) {
    int t = t0 + rw * 16 + q * 4 + r;
    float s1 = 0.f, s2 = 0.f;
#pragma unroll
    for (int nt = 0; nt < 4; nt++) {
      int col = wcol + nt * 16 + ln;
      float resid = (t < L_SEQ) ? H1[((size_t)b * L_SEQ + t) * 128 + col] : 0.f;
      float v = acc[nt][r] + b2[l * 128 + col] + resid;
      vres[r][nt] = v;
      s1 += v;
      s2 += v * v;
    }
#pragma unroll
    for (int m = 1; m < 16; m <<= 1) {
      s1 += __shfl_xor(s1, m);
      s2 += __shfl_xor(s2, m);
    }
    s1r[r] = s1; s2r[r] = s2;
  }
  __syncthreads();
  if (ln == 0) {
#pragma unroll
    for (int r = 0; r < 4; r++) {
      Ssum[cw][rw * 16 + q * 4 + r][0] = s1r[r];
      Ssum[cw][rw * 16 + q * 4 + r][1] = s2r[r];
    }
  }
  __syncthreads();
#pragma unroll
  for (int r = 0; r < 4; r++) {
    int row = rw * 16 + q * 4 + r;
    float s1 = s1r[r] + Ssum[cw ^ 1][row][0];
    float s2 = s2r[r] + Ssum[cw ^ 1][row][1];
    float mean = s1 * (1.f / 128.f);
    float rstd = rsqrtf(s2 * (1.f / 128.f) - mean * mean + 1e-5f);
    int t = t0 + row;
    if (t < L_SEQ) {
#pragma unroll
      for (int nt = 0; nt < 4; nt++) {
        int col = wcol + nt * 16 + ln;
        Hout[((size_t)b * L_SEQ + t) * 128 + col] =
            (vres[r][nt] - mean) * rstd * nw[col] + nbv[col];
      }
    }
  }
}

// ---------------------------------------------------------------------------
// k_final  (round-3, proven)
// ---------------------------------------------------------------------------
__global__ __launch_bounds__(256) void k_final(
    const float* __restrict__ Hsrc, const float* __restrict__ fw,
    const float* __restrict__ fb, const float* __restrict__ pw,
    const float* __restrict__ pb, float* __restrict__ out) {
  int b = blockIdx.y;
  int v0 = blockIdx.x * 16;
  int tid = threadIdx.x;
  __shared__ float At[128][17];
  __shared__ float Ws[32][97];
  __shared__ float Os[96][17];
  for (int i = 0; i < 8; i++) {
    int e = tid + i * 256;
    int k = e & 127, tl = e >> 7;
    At[k][tl] = Hsrc[((size_t)b * L_SEQ + v0 + tl) * 128 + k];
  }
  __syncthreads();
  {
    int g = tid & 15, tl = tid >> 4;
    float s1 = 0.f, s2 = 0.f;
#pragma unroll
    for (int kk = 0; kk < 8; kk++) {
      float v = At[g * 8 + kk][tl];
      s1 += v;
      s2 += v * v;
    }
#pragma unroll
    for (int msk = 1; msk < 16; msk <<= 1) {
      s1 += __shfl_xor(s1, msk);
      s2 += __shfl_xor(s2, msk);
    }
    float mean = s1 * (1.f / 128.f);
    float rstd = rsqrtf(s2 * (1.f / 128.f) - mean * mean + 1e-5f);
#pragma unroll
    for (int kk = 0; kk < 8; kk++) {
      int k = g * 8 + kk;
      At[k][tl] = (At[k][tl] - mean) * rstd * fw[k] + fb[k];
    }
  }
  __syncthreads();
  int tm = tid & 15, tt = tid >> 4;
  float acc[6] = {0.f};
  for (int k0 = 0; k0 < 128; k0 += 32) {
    for (int i = 0; i < 12; i++) {
      int e = tid + i * 256;
      int ki = e & 31, p = e >> 5;
      Ws[ki][p] = pw[(size_t)p * 128 + k0 + ki];
    }
    __syncthreads();
    for (int ki = 0; ki < 32; ki++) {
      float a = At[k0 + ki][tt];
#pragma unroll
      for (int jq = 0; jq < 6; jq++)
        acc[jq] = fmaf(a, Ws[ki][tm + jq * 16], acc[jq]);
    }
    __syncthreads();
  }
#pragma unroll
  for (int jq = 0; jq < 6; jq++) {
    int p = tm + jq * 16;
    Os[p][tt] = acc[jq] + pb[p];
  }
  __syncthreads();
  for (int i = 0; i < 6; i++) {
    int e = tid + i * 256;
    int vi = e & 15, p = e >> 4;
    out[((size_t)b * 96 + p) * 1024 + v0 + vi] = Os[p][vi];
  }
}

// ---------------------------------------------------------------------------
extern "C" void kernel_launch(void* const* d_in, const int* in_sizes, int n_in,
                              void* d_out, int out_size, void* d_ws, size_t ws_size,
                              hipStream_t stream) {
  (void)in_sizes; (void)n_in; (void)out_size; (void)ws_size;
  const float* x_enc  = (const float*)d_in[0];
  const float* x_mark = (const float*)d_in[1];
  const float* emb_w  = (const float*)d_in[4];
  const float* emb_b  = (const float*)d_in[5];
  const float* ipw    = (const float*)d_in[6];
  const float* cw     = (const float*)d_in[7];
  const float* cb     = (const float*)d_in[8];
  const float* xpw    = (const float*)d_in[9];
  const float* dpw    = (const float*)d_in[10];
  const float* dpb    = (const float*)d_in[11];
  const float* A_log  = (const float*)d_in[12];
  const float* Dpar   = (const float*)d_in[13];
  const float* opw    = (const float*)d_in[14];
  const float* n1w    = (const float*)d_in[15];
  const float* n1b    = (const float*)d_in[16];
  const float* n2w    = (const float*)d_in[17];
  const float* n2b    = (const float*)d_in[18];
  const float* fw1    = (const float*)d_in[19];
  const float* fb1    = (const float*)d_in[20];
  const float* fw2    = (const float*)d_in[21];
  const float* fb2    = (const float*)d_in[22];
  const float* fnw    = (const float*)d_in[23];
  const float* fnb    = (const float*)d_in[24];
  const float* pw     = (const float*)d_in[25];
  const float* pb     = (const float*)d_in[26];

  float* ws   = (float*)d_ws;
  float* H    = ws + OFF_H;
  float* H1   = ws + OFF_H1;
  float* XZ   = ws + OFF_XZ;
  float* XCT  = ws + OFF_XCT;
  float* DLT  = ws + OFF_DLT;
  float* BmT  = ws + OFF_BMT;
  float* CmT  = ws + OFF_CMT;
  float* YT   = ws + OFF_YT;
  float* sumH = ws + OFF_H1;             // overlay: H1 unused during scan

  k_embed<<<dim3(33, 8), 256, 0, stream>>>(x_enc, x_mark, emb_w, emb_b, H);
  for (int l = 0; l < 2; l++) {
    k_xz<<<dim3(33, 8, 4), 256, 0, stream>>>(H, ipw, XZ, l);
    k_mid<<<dim3(36, 8, 2), 256, 0, stream>>>(XZ, cw, cb, xpw, dpw, dpb,
                                              XCT, DLT, BmT, CmT, l);
    k_scan1<<<dim3(16, 8, 64), 64, 0, stream>>>(DLT, XCT, BmT, A_log,
                                                sumH, YT, l);
    k_scan2<<<dim3(16, 8, 64), 64, 0, stream>>>(DLT, XCT, BmT, CmT, XZ,
                                                A_log, Dpar, sumH, YT, l);
    k_out<<<dim3(33, 8), 256, 0, stream>>>(YT, H, opw, n1w, n1b, H1, l);
    k_ffn<<<dim3(33, 8), 256, 0, stream>>>(H1, fw1, fb1, fw2, fb2, n2w, n2b, H, l);
  }
  k_final<<<dim3(64, 8), 256, 0, stream>>>(H, fnw, fnb, pw, pb, (float*)d_out);
}

// Round 10
// 407.738 us; speedup vs baseline: 1.0240x; 1.0240x over previous
//
#include <hip/hip_runtime.h>
#include <math.h>

// ---------------------------------------------------------------------------
// Bidirectional Mamba encoder, round 10.
// Round-8/9 bf16-MFMA GEMMs kept. Scan restructured as THREE passes:
//   k_scan1: per-chunk local scan from h=0 -> h_end + sum(delta)  (32 chunks)
//   k_scanp: O(NCH) exclusive-prefix walk converting sumH in place from
//            h_end to h_init (one wave per dir,b,8d; 32 serial steps)
//   k_scan2: loads h_init directly (no per-chunk rebuild), re-runs chunk,
//            gates with silu(z), writes Y[t][d].
// scan1/scan2 packed 4 chunk-waves per 256-thread block -> 32 waves/CU
// (single-wave workgroups cap at ~16 workgroups/CU; round-9 lesson).
// ---------------------------------------------------------------------------

#define L_SEQ 1031
#define LP    1152          // 32 chunks x 36
#define TC    36
#define NCH   32
#define SDROW 1056          // first YT tail row used for sdl stash
#define BATCH 8
#define NVAR  1024
#define SEQQ  512
#define TFEAT 7

#define SZ_H    ((size_t)BATCH * L_SEQ * 128)
#define SZ_XZ   ((size_t)2 * BATCH * L_SEQ * 256)
#define SZ_DT   ((size_t)2 * BATCH * 128 * LP)
#define SZ_BC   ((size_t)2 * BATCH * 16 * LP)
#define OFF_H    ((size_t)0)
#define OFF_H1   (OFF_H + SZ_H)
#define OFF_XZ   (OFF_H1 + SZ_H)
#define OFF_XCT  (OFF_XZ + SZ_XZ)
#define OFF_DLT  (OFF_XCT + SZ_DT)
#define OFF_BMT  (OFF_DLT + SZ_DT)
#define OFF_CMT  (OFF_BMT + SZ_BC)
#define OFF_YT   (OFF_CMT + SZ_BC)
#define SZ_SUM  ((size_t)2 * BATCH * NCH * 128 * 16)   // 1,048,576 <= SZ_H

typedef __bf16 bf16_t;
typedef bf16_t bf16x4 __attribute__((ext_vector_type(4)));
typedef bf16_t bf16x8 __attribute__((ext_vector_type(8)));
typedef float floatx4 __attribute__((ext_vector_type(4)));

#define MFMA16(a, b, c) __builtin_amdgcn_mfma_f32_16x16x32_bf16((a), (b), (c), 0, 0, 0)

__device__ __forceinline__ float silu_f(float x) {
  return x / (1.f + __expf(-x));
}
__device__ __forceinline__ float softplus_f(float x) {
  return (x > 20.f) ? x : log1pf(__expf(x));
}
__device__ __forceinline__ float red8(float x) {
  x += __int_as_float(__builtin_amdgcn_update_dpp(
      0, __float_as_int(x), 0xB1, 0xF, 0xF, true));   // quad_perm [1,0,3,2]
  x += __int_as_float(__builtin_amdgcn_update_dpp(
      0, __float_as_int(x), 0x4E, 0xF, 0xF, true));   // quad_perm [2,3,0,1]
  x += __int_as_float(__builtin_amdgcn_update_dpp(
      0, __float_as_int(x), 0x141, 0xF, 0xF, true));  // row_half_mirror
  return x;
}

// Stage 128xK-chunk of a row-major [N][K] fp32 weight into Wbf (bf16).
#define STAGE_W128(WBUF, SRC, LDK, K0)                                       \
  _Pragma("unroll")                                                          \
  for (int i_ = 0; i_ < 16; i_++) {                                          \
    int e_ = tid + i_ * 256;                                                 \
    int n_ = e_ >> 5, kq_ = e_ & 31;                                         \
    float4 wv_ = *(const float4*)&(SRC)[(size_t)n_ * (LDK) + (K0) + kq_ * 4];\
    bf16x4 bv_ = {(bf16_t)wv_.x, (bf16_t)wv_.y, (bf16_t)wv_.z, (bf16_t)wv_.w};\
    *(bf16x4*)&WBUF[n_][kq_ * 4] = bv_;                                      \
  }

// 16 MFMAs: full K=128 panel for this wave's 16x64 output.
#define MFMA_K128(ABUF, WBUF, ACC)                                           \
  _Pragma("unroll")                                                          \
  for (int kc_ = 0; kc_ < 4; kc_++) {                                        \
    bf16x8 a_ = *(const bf16x8*)&ABUF[arow][kc_ * 32 + q8];                  \
    _Pragma("unroll")                                                        \
    for (int nt_ = 0; nt_ < 4; nt_++) {                                      \
      bf16x8 b_ = *(const bf16x8*)&WBUF[wcol + nt_ * 16 + ln][kc_ * 32 + q8];\
      ACC[nt_] = MFMA16(a_, b_, ACC[nt_]);                                   \
    }                                                                        \
  }

// ---------------------------------------------------------------------------
// k_embed  (round-8, proven)
// ---------------------------------------------------------------------------
__global__ __launch_bounds__(256) void k_embed(
    const float* __restrict__ x_enc, const float* __restrict__ x_mark,
    const float* __restrict__ emb_w, const float* __restrict__ emb_b,
    float* __restrict__ H) {
  int b = blockIdx.y;
  int v0 = blockIdx.x * 32;
  int tid = threadIdx.x;
  __shared__ bf16_t Abf[32][136];
  __shared__ bf16_t Wbf[128][136];
  int lane = tid & 63, ln = lane & 15, q = lane >> 4, q8 = q * 8;
  int w = tid >> 6, rw = w & 1, cw = w >> 1;
  int arow = rw * 16 + ln, wcol = cw * 64;
  floatx4 acc[4];
#pragma unroll
  for (int nt = 0; nt < 4; nt++) acc[nt] = (floatx4){0.f, 0.f, 0.f, 0.f};

  for (int c = 0; c < 4; c++) {
    int s0 = c * 128;
#pragma unroll
    for (int i = 0; i < 4; i++) {
      int e = tid + i * 256;
      int s = e >> 3, vq = e & 7;
      int vg = v0 + vq * 4;
      float4 xv;
      if (vg + 3 < NVAR) {
        xv = *(const float4*)&x_enc[((size_t)b * SEQQ + s0 + s) * NVAR + vg];
        if (xv.x == -9999.f) xv.x = -1.f;
        if (xv.y == -9999.f) xv.y = -1.f;
        if (xv.z == -9999.f) xv.z = -1.f;
        if (xv.w == -9999.f) xv.w = -1.f;
      } else {
        float tmp[4];
#pragma unroll
        for (int u = 0; u < 4; u++) {
          int v = vg + u;
          tmp[u] = (v < L_SEQ)
                       ? x_mark[((size_t)b * SEQQ + s0 + s) * TFEAT + (v - NVAR)]
                       : 0.f;
        }
        xv = make_float4(tmp[0], tmp[1], tmp[2], tmp[3]);
      }
      Abf[vq * 4 + 0][s] = (bf16_t)xv.x;
      Abf[vq * 4 + 1][s] = (bf16_t)xv.y;
      Abf[vq * 4 + 2][s] = (bf16_t)xv.z;
      Abf[vq * 4 + 3][s] = (bf16_t)xv.w;
    }
    STAGE_W128(Wbf, emb_w, SEQQ, s0);
    __syncthreads();
    MFMA_K128(Abf, Wbf, acc);
    __syncthreads();
  }
#pragma unroll
  for (int r = 0; r < 4; r++) {
    int v = v0 + rw * 16 + q * 4 + r;
    if (v < L_SEQ) {
      float* dst = &H[((size_t)b * L_SEQ + v) * 128];
#pragma unroll
      for (int nt = 0; nt < 4; nt++) {
        int col = wcol + nt * 16 + ln;
        dst[col] = acc[nt][r] + emb_b[col];
      }
    }
  }
}

// ---------------------------------------------------------------------------
// k_xz  (round-8, proven)
// ---------------------------------------------------------------------------
__global__ __launch_bounds__(256) void k_xz(
    const float* __restrict__ H, const float* __restrict__ ipw,
    float* __restrict__ XZ, int l) {
  int b = blockIdx.y;
  int dir = blockIdx.z >> 1, nh = blockIdx.z & 1;
  int t0 = blockIdx.x * 32;
  int tid = threadIdx.x;
  __shared__ bf16_t Abf[32][136];
  __shared__ bf16_t Wbf[128][136];
  int lane = tid & 63, ln = lane & 15, q = lane >> 4, q8 = q * 8;
  int w = tid >> 6, rw = w & 1, cw = w >> 1;
  int arow = rw * 16 + ln, wcol = cw * 64;
  floatx4 acc[4];
#pragma unroll
  for (int nt = 0; nt < 4; nt++) acc[nt] = (floatx4){0.f, 0.f, 0.f, 0.f};
  const float* wbase = ipw + (size_t)(l * 2 + dir) * 256 * 128 + (size_t)nh * 128 * 128;

#pragma unroll
  for (int i = 0; i < 4; i++) {
    int e = tid + i * 256;
    int tl = e >> 5, kq = e & 31;
    int t = t0 + tl;
    float4 hv = make_float4(0.f, 0.f, 0.f, 0.f);
    if (t < L_SEQ) {
      int st = dir ? (L_SEQ - 1 - t) : t;
      hv = *(const float4*)&H[((size_t)b * L_SEQ + st) * 128 + kq * 4];
    }
    bf16x4 av = {(bf16_t)hv.x, (bf16_t)hv.y, (bf16_t)hv.z, (bf16_t)hv.w};
    *(bf16x4*)&Abf[tl][kq * 4] = av;
  }
  STAGE_W128(Wbf, wbase, 128, 0);
  __syncthreads();
  MFMA_K128(Abf, Wbf, acc);

#pragma unroll
  for (int r = 0; r < 4; r++) {
    int t = t0 + rw * 16 + q * 4 + r;
    if (t < L_SEQ) {
      float* dst = XZ + ((size_t)(dir * BATCH + b) * L_SEQ + t) * 256 + nh * 128;
#pragma unroll
      for (int nt = 0; nt < 4; nt++) dst[wcol + nt * 16 + ln] = acc[nt][r];
    }
  }
}

// ---------------------------------------------------------------------------
// k_mid  (round-5, proven; grid (36,8,2) covers LP=1152)
// ---------------------------------------------------------------------------
__global__ __launch_bounds__(256) void k_mid(
    const float* __restrict__ XZ,
    const float* __restrict__ conv_w, const float* __restrict__ conv_b,
    const float* __restrict__ xpw,
    const float* __restrict__ dpw, const float* __restrict__ dpb,
    float* __restrict__ XCT, float* __restrict__ DLT,
    float* __restrict__ BmT, float* __restrict__ CmT, int l) {
  int b = blockIdx.y, dir = blockIdx.z;
  int t0 = blockIdx.x * 32;
  int tid = threadIdx.x;
  int pg = l * 2 + dir;
  __shared__ float xcs[32][132];
  __shared__ float xpws[40][128];
  __shared__ float dbcs[40][36];
  const float* xz = XZ + (size_t)(dir * BATCH + b) * L_SEQ * 256;

  for (int i = 0; i < 20; i++) {
    int e = tid + i * 256;
    int k = e & 127, j = e >> 7;
    xpws[j][k] = xpw[((size_t)pg * 40 + j) * 128 + k];
  }
  for (int i = 0; i < 16; i++) {
    int e = tid + i * 256;
    int d = e & 127, tl = e >> 7;
    int t = t0 + tl;
    float v = 0.f;
    if (t < L_SEQ) {
      float x1 = xz[(size_t)t * 256 + d];
      float x0 = (t > 0) ? xz[(size_t)(t - 1) * 256 + d] : 0.f;
      float c0 = conv_w[((size_t)pg * 128 + d) * 2 + 0];
      float c1 = conv_w[((size_t)pg * 128 + d) * 2 + 1];
      v = silu_f(x0 * c0 + x1 * c1 + conv_b[(size_t)pg * 128 + d]);
    }
    xcs[tl][d] = v;
  }
  __syncthreads();
  {
    int tl = tid & 31, jg = tid >> 5;
    float acc[5] = {0.f};
    const float4* xrow = (const float4*)&xcs[tl][0];
    for (int kk = 0; kk < 32; kk++) {
      float4 a = xrow[kk];
#pragma unroll
      for (int jj = 0; jj < 5; jj++) {
        float4 w = ((const float4*)&xpws[jg * 5 + jj][0])[kk];
        acc[jj] = fmaf(a.x, w.x, acc[jj]);
        acc[jj] = fmaf(a.y, w.y, acc[jj]);
        acc[jj] = fmaf(a.z, w.z, acc[jj]);
        acc[jj] = fmaf(a.w, w.w, acc[jj]);
      }
    }
#pragma unroll
    for (int jj = 0; jj < 5; jj++) dbcs[jg * 5 + jj][tl] = acc[jj];
  }
  __syncthreads();
  for (int i = 0; i < 4; i++) {
    int e = tid + i * 256;
    int tl = e & 31, r = e >> 5;
    int n = r & 15, isC = r >> 4;
    int t = t0 + tl;
    if (t < LP) {
      float v = dbcs[8 + isC * 16 + n][tl];
      float* dst = isC ? CmT : BmT;
      dst[((size_t)(dir * BATCH + b) * 16 + n) * LP + t] = v;
    }
  }
  {
    int d = tid & 127, th = tid >> 7;
    float dw[8];
#pragma unroll
    for (int k = 0; k < 8; k++) dw[k] = dpw[((size_t)pg * 128 + d) * 8 + k];
    float dbv = dpb[(size_t)pg * 128 + d];
    size_t base = ((size_t)(dir * BATCH + b) * 128 + d) * LP;
    for (int tb = th * 16; tb < th * 16 + 16; tb += 4) {
      int t = t0 + tb;
      if (t < LP) {
        float dv[4], xv[4];
#pragma unroll
        for (int u = 0; u < 4; u++) {
          int tl = tb + u;
          float a = dbv;
#pragma unroll
          for (int k = 0; k < 8; k++) a = fmaf(dbcs[k][tl], dw[k], a);
          dv[u] = softplus_f(a);
          xv[u] = xcs[tl][d];
        }
        *(float4*)(DLT + base + t) = make_float4(dv[0], dv[1], dv[2], dv[3]);
        *(float4*)(XCT + base + t) = make_float4(xv[0], xv[1], xv[2], xv[3]);
      }
    }
  }
}

// ---------------------------------------------------------------------------
// k_scan1: per-chunk local scan from h=0 -> h_end (sumH) + sum(delta)
// (YT tail). 4 chunk-waves per block. grid (16, 8, 16) z=(dir,jg), blk 256.
// ---------------------------------------------------------------------------
__global__ __launch_bounds__(256) void k_scan1(
    const float* __restrict__ DLT, const float* __restrict__ XCT,
    const float* __restrict__ BmT,
    const float* __restrict__ A_log,
    float* __restrict__ sumH, float* __restrict__ YT, int l) {
  int tid = threadIdx.x;
  int wid = tid >> 6;
  int lane = tid & 63;
  int z = blockIdx.z;
  int dir = z >> 3, jg = z & 7;
  int j = jg * 4 + wid;
  int b = blockIdx.y;
  int np = lane & 7, ds = lane >> 3;
  int d = blockIdx.x * 8 + ds;
  int pg = l * 2 + dir;
  int n0 = np * 2;
  int dirb = dir * BATCH + b;
  float A0 = -__expf(A_log[((size_t)pg * 128 + d) * 16 + n0]);
  float A1 = -__expf(A_log[((size_t)pg * 128 + d) * 16 + n0 + 1]);
  size_t bd = ((size_t)dirb * 128 + d) * LP + (size_t)j * TC;
  size_t bn = ((size_t)dirb * 16 + n0) * LP + (size_t)j * TC;
  const float4* dl4 = (const float4*)(DLT + bd);
  const float4* xc4 = (const float4*)(XCT + bd);
  const float4* b04 = (const float4*)(BmT + bn);
  const float4* b14 = (const float4*)(BmT + bn + LP);
  float h0 = 0.f, h1 = 0.f, sdl = 0.f;
  const int NI = TC / 4;   // 9
  float4 cd = dl4[0], cx = xc4[0], cb0 = b04[0], cb1 = b14[0];
#define P1STEP(DL, XC, B0, B1)                       \
  {                                                  \
    float du_ = (DL) * (XC);                         \
    h0 = fmaf(__expf((DL) * A0), h0, du_ * (B0));    \
    h1 = fmaf(__expf((DL) * A1), h1, du_ * (B1));    \
  }
  for (int i = 0; i < NI; i++) {
    float4 nd = cd, nx = cx, nb0 = cb0, nb1 = cb1;
    if (i + 1 < NI) {
      nd = dl4[i + 1]; nx = xc4[i + 1];
      nb0 = b04[i + 1]; nb1 = b14[i + 1];
    }
    P1STEP(cd.x, cx.x, cb0.x, cb1.x);
    P1STEP(cd.y, cx.y, cb0.y, cb1.y);
    P1STEP(cd.z, cx.z, cb0.z, cb1.z);
    P1STEP(cd.w, cx.w, cb0.w, cb1.w);
    sdl += (cd.x + cd.y) + (cd.z + cd.w);
    cd = nd; cx = nx; cb0 = nb0; cb1 = nb1;
  }
#undef P1STEP
  size_t si = (((size_t)dirb * NCH + j) * 128 + d) * 16 + n0;
  *(float2*)&sumH[si] = make_float2(h0, h1);
  if (np == 0) {
    YT[((size_t)dirb * LP + SDROW + j) * 128 + d] = sdl;
  }
}

// ---------------------------------------------------------------------------
// k_scanp: exclusive-prefix walk over chunk summaries, converting sumH
// in place from h_end[j] to h_init[j]. One wave per (dir,b,8d).
// grid (16, 8, 2) z=dir, block 64. 32 serial steps.
// ---------------------------------------------------------------------------
__global__ __launch_bounds__(64) void k_scanp(
    const float* __restrict__ A_log, float* __restrict__ sumH,
    const float* __restrict__ YT, int l) {
  int dir = blockIdx.z, b = blockIdx.y;
  int lane = threadIdx.x;
  int np = lane & 7, ds = lane >> 3;
  int d = blockIdx.x * 8 + ds;
  int pg = l * 2 + dir;
  int n0 = np * 2;
  int dirb = dir * BATCH + b;
  float A0 = -__expf(A_log[((size_t)pg * 128 + d) * 16 + n0]);
  float A1 = -__expf(A_log[((size_t)pg * 128 + d) * 16 + n0 + 1]);
  size_t sbase = (((size_t)dirb * NCH) * 128 + d) * 16 + n0;
  const float* sdbase = YT + ((size_t)dirb * LP + SDROW) * 128 + d;
  float h0 = 0.f, h1 = 0.f;
  // depth-1 prefetch on the (independent) summary loads
  float2 hE = *(const float2*)&sumH[sbase];
  float sdl = sdbase[0];
  for (int j = 0; j < NCH; j++) {
    float2 hEn;
    float sdln;
    if (j + 1 < NCH) {
      hEn = *(const float2*)&sumH[sbase + (size_t)(j + 1) * 2048];
      sdln = sdbase[(size_t)(j + 1) * 128];
    }
    *(float2*)&sumH[sbase + (size_t)j * 2048] = make_float2(h0, h1);
    h0 = fmaf(__expf(A0 * sdl), h0, hE.x);
    h1 = fmaf(__expf(A1 * sdl), h1, hE.y);
    hE = hEn;
    sdl = sdln;
  }
}

// ---------------------------------------------------------------------------
// k_scan2: load h_init directly, re-run chunk, DPP-reduce, gate silu(z),
// write Y[t][d]. 4 chunk-waves per block. grid (16, 8, 16), block 256.
// ---------------------------------------------------------------------------
__global__ __launch_bounds__(256) void k_scan2(
    const float* __restrict__ DLT, const float* __restrict__ XCT,
    const float* __restrict__ BmT, const float* __restrict__ CmT,
    const float* __restrict__ XZ,
    const float* __restrict__ A_log, const float* __restrict__ Dpar,
    const float* __restrict__ sumH,
    float* __restrict__ YT, int l) {
  int tid = threadIdx.x;
  int wid = tid >> 6;
  int lane = tid & 63;
  int z = blockIdx.z;
  int dir = z >> 3, jg = z & 7;
  int j = jg * 4 + wid;
  int b = blockIdx.y;
  int np = lane & 7, ds = lane >> 3;
  int d = blockIdx.x * 8 + ds;
  int pg = l * 2 + dir;
  int n0 = np * 2;
  int dirb = dir * BATCH + b;
  float A0 = -__expf(A_log[((size_t)pg * 128 + d) * 16 + n0]);
  float A1 = -__expf(A_log[((size_t)pg * 128 + d) * 16 + n0 + 1]);
  float Dv = Dpar[(size_t)pg * 128 + d];
  float2 hi = *(const float2*)&sumH[(((size_t)dirb * NCH + j) * 128 + d) * 16 + n0];
  float h0 = hi.x, h1 = hi.y;
  size_t bd = ((size_t)dirb * 128 + d) * LP + (size_t)j * TC;
  size_t bn = ((size_t)dirb * 16 + n0) * LP + (size_t)j * TC;
  const float4* dl4 = (const float4*)(DLT + bd);
  const float4* xc4 = (const float4*)(XCT + bd);
  const float4* b04 = (const float4*)(BmT + bn);
  const float4* b14 = (const float4*)(BmT + bn + LP);
  const float4* c04 = (const float4*)(CmT + bn);
  const float4* c14 = (const float4*)(CmT + bn + LP);
  const float* zbase = XZ + (size_t)dirb * L_SEQ * 256 + 128 + d
                       + (size_t)j * TC * 256;
  float* ybase = YT + ((size_t)dirb * LP + (size_t)j * TC) * 128 + d;
  const int NI = TC / 4;   // 9
  float4 cd = dl4[0], cx = xc4[0], cb0 = b04[0], cb1 = b14[0];
  float4 cc0 = c04[0], cc1 = c14[0];
  float zc[4], zn[4];
  if (np == 0) {
#pragma unroll
    for (int u = 0; u < 4; u++) zc[u] = zbase[(size_t)u * 256];
  }
#define STEP1(DL, XC, B0, B1, C0, C1, YO)            \
  {                                                  \
    float du_ = (DL) * (XC);                         \
    h0 = fmaf(__expf((DL) * A0), h0, du_ * (B0));    \
    h1 = fmaf(__expf((DL) * A1), h1, du_ * (B1));    \
    float p_ = red8(fmaf(h1, (C1), h0 * (C0)));      \
    (YO) = fmaf(Dv, (XC), p_);                       \
  }
  for (int i = 0; i < NI; i++) {
    float4 nd = cd, nx = cx, nb0 = cb0, nb1 = cb1, nc0 = cc0, nc1 = cc1;
    if (i + 1 < NI) {
      nd = dl4[i + 1]; nx = xc4[i + 1];
      nb0 = b04[i + 1]; nb1 = b14[i + 1];
      nc0 = c04[i + 1]; nc1 = c14[i + 1];
      if (np == 0) {
        int tb = (i + 1) * 4;
#pragma unroll
        for (int u = 0; u < 4; u++) zn[u] = zbase[(size_t)(tb + u) * 256];
      }
    }
    float4 y;
    STEP1(cd.x, cx.x, cb0.x, cb1.x, cc0.x, cc1.x, y.x);
    STEP1(cd.y, cx.y, cb0.y, cb1.y, cc0.y, cc1.y, y.y);
    STEP1(cd.z, cx.z, cb0.z, cb1.z, cc0.z, cc1.z, y.z);
    STEP1(cd.w, cx.w, cb0.w, cb1.w, cc0.w, cc1.w, y.w);
    if (np == 0) {
      int tg = j * TC + i * 4;
      float yv[4] = {y.x * silu_f(zc[0]), y.y * silu_f(zc[1]),
                     y.z * silu_f(zc[2]), y.w * silu_f(zc[3])};
#pragma unroll
      for (int u = 0; u < 4; u++) {
        if (tg + u < SDROW) ybase[(size_t)(i * 4 + u) * 128] = yv[u];
      }
#pragma unroll
      for (int u = 0; u < 4; u++) zc[u] = zn[u];
    }
    cd = nd; cx = nx; cb0 = nb0; cb1 = nb1; cc0 = nc0; cc1 = nc1;
  }
#undef STEP1
}

// ---------------------------------------------------------------------------
// k_out  (round-8, proven)
// ---------------------------------------------------------------------------
__global__ __launch_bounds__(256) void k_out(
    const float* __restrict__ YT, const float* __restrict__ Hin,
    const float* __restrict__ opw,
    const float* __restrict__ n1w, const float* __restrict__ n1b,
    float* __restrict__ H1, int l) {
  int b = blockIdx.y;
  int t0 = blockIdx.x * 32;
  int tid = threadIdx.x;
  __shared__ bf16_t Abf[32][136];
  __shared__ bf16_t Wbf[128][136];
  __shared__ float Ssum[2][32][2];
  int lane = tid & 63, ln = lane & 15, q = lane >> 4, q8 = q * 8;
  int w = tid >> 6, rw = w & 1, cw = w >> 1;
  int arow = rw * 16 + ln, wcol = cw * 64;
  floatx4 acc[4];
#pragma unroll
  for (int nt = 0; nt < 4; nt++) acc[nt] = (floatx4){0.f, 0.f, 0.f, 0.f};

  for (int dirp = 0; dirp < 2; dirp++) {
    const float* ysrc = YT + (size_t)(dirp * BATCH + b) * LP * 128;
#pragma unroll
    for (int i = 0; i < 4; i++) {
      int e = tid + i * 256;
      int tl = e >> 5, dq = e & 31;
      int tg = t0 + tl;
      int srow = dirp ? (L_SEQ - 1 - tg) : tg;
      float4 yv = make_float4(0.f, 0.f, 0.f, 0.f);
      if (srow >= 0) yv = *(const float4*)&ysrc[(size_t)srow * 128 + dq * 4];
      bf16x4 av = {(bf16_t)yv.x, (bf16_t)yv.y, (bf16_t)yv.z, (bf16_t)yv.w};
      *(bf16x4*)&Abf[tl][dq * 4] = av;
    }
    const float* wsrc = opw + (size_t)(l * 2 + dirp) * 128 * 128;
    STAGE_W128(Wbf, wsrc, 128, 0);
    __syncthreads();
    MFMA_K128(Abf, Wbf, acc);
    __syncthreads();
  }
  const float* nw = n1w + l * 128;
  const float* nbv = n1b + l * 128;
  float vres[4][4];
  float s1r[4], s2r[4];
#pragma unroll
  for (int r = 0; r < 4; r++) {
    int t = t0 + rw * 16 + q * 4 + r;
    float s1 = 0.f, s2 = 0.f;
#pragma unroll
    for (int nt = 0; nt < 4; nt++) {
      int col = wcol + nt * 16 + ln;
      float resid = (t < L_SEQ) ? Hin[((size_t)b * L_SEQ + t) * 128 + col] : 0.f;
      float v = acc[nt][r] + resid;
      vres[r][nt] = v;
      s1 += v;
      s2 += v * v;
    }
#pragma unroll
    for (int m = 1; m < 16; m <<= 1) {
      s1 += __shfl_xor(s1, m);
      s2 += __shfl_xor(s2, m);
    }
    s1r[r] = s1; s2r[r] = s2;
  }
  if (ln == 0) {
#pragma unroll
    for (int r = 0; r < 4; r++) {
      Ssum[cw][rw * 16 + q * 4 + r][0] = s1r[r];
      Ssum[cw][rw * 16 + q * 4 + r][1] = s2r[r];
    }
  }
  __syncthreads();
#pragma unroll
  for (int r = 0; r < 4; r++) {
    int row = rw * 16 + q * 4 + r;
    float s1 = s1r[r] + Ssum[cw ^ 1][row][0];
    float s2 = s2r[r] + Ssum[cw ^ 1][row][1];
    float mean = s1 * (1.f / 128.f);
    float rstd = rsqrtf(s2 * (1.f / 128.f) - mean * mean + 1e-5f);
    int t = t0 + row;
    if (t < L_SEQ) {
#pragma unroll
      for (int nt = 0; nt < 4; nt++) {
        int col = wcol + nt * 16 + ln;
        H1[((size_t)b * L_SEQ + t) * 128 + col] =
            (vres[r][nt] - mean) * rstd * nw[col] + nbv[col];
      }
    }
  }
}

// ---------------------------------------------------------------------------
// k_ffn  (round-8, proven)
// ---------------------------------------------------------------------------
__global__ __launch_bounds__(256) void k_ffn(
    const float* __restrict__ H1, const float* __restrict__ w1,
    const float* __restrict__ b1, const float* __restrict__ w2,
    const float* __restrict__ b2, const float* __restrict__ n2w,
    const float* __restrict__ n2b, float* __restrict__ Hout, int l) {
  int b = blockIdx.y;
  int t0 = blockIdx.x * 32;
  int tid = threadIdx.x;
  __shared__ bf16_t Abf[32][136];
  __shared__ bf16_t Wbf[128][136];
  __shared__ bf16_t Ut[32][136];
  __shared__ float Ssum[2][32][2];
  int lane = tid & 63, ln = lane & 15, q = lane >> 4, q8 = q * 8;
  int w = tid >> 6, rw = w & 1, cw = w >> 1;
  int arow = rw * 16 + ln, wcol = cw * 64;
  floatx4 acc[4];
#pragma unroll
  for (int nt = 0; nt < 4; nt++) acc[nt] = (floatx4){0.f, 0.f, 0.f, 0.f};
  const float* w1b = w1 + (size_t)l * 128 * 128;
  const float* w2b = w2 + (size_t)l * 128 * 128;

#pragma unroll
  for (int i = 0; i < 4; i++) {
    int e = tid + i * 256;
    int tl = e >> 5, kq = e & 31;
    int t = t0 + tl;
    float4 hv = make_float4(0.f, 0.f, 0.f, 0.f);
    if (t < L_SEQ)
      hv = *(const float4*)&H1[((size_t)b * L_SEQ + t) * 128 + kq * 4];
    bf16x4 av = {(bf16_t)hv.x, (bf16_t)hv.y, (bf16_t)hv.z, (bf16_t)hv.w};
    *(bf16x4*)&Abf[tl][kq * 4] = av;
  }
  STAGE_W128(Wbf, w1b, 128, 0);
  __syncthreads();
  MFMA_K128(Abf, Wbf, acc);
  __syncthreads();
  {
    float b1v[4];
#pragma unroll
    for (int nt = 0; nt < 4; nt++) b1v[nt] = b1[l * 128 + wcol + nt * 16 + ln];
#pragma unroll
    for (int nt = 0; nt < 4; nt++) {
#pragma unroll
      for (int r = 0; r < 4; r++) {
        Ut[rw * 16 + q * 4 + r][wcol + nt * 16 + ln] =
            (bf16_t)fmaxf(acc[nt][r] + b1v[nt], 0.f);
      }
      acc[nt] = (floatx4){0.f, 0.f, 0.f, 0.f};
    }
  }
  STAGE_W128(Wbf, w2b, 128, 0);
  __syncthreads();
  MFMA_K128(Ut, Wbf, acc);
  const float* nw = n2w + l * 128;
  const float* nbv = n2b + l * 128;
  float vres[4][4];
  float s1r[4], s2r[4];
#pragma unroll
  for (int r = 0; r < 4; r++) {
    int t = t0 + rw * 16 + q * 4 + r;
    float s1 = 0.f, s2 = 0.f;
#pragma unroll
    for (int nt = 0; nt < 4; nt++) {
      int col = wcol + nt * 16 + ln;
      float resid = (t < L_SEQ) ? H1[((size_t)b * L_SEQ + t) * 128 + col] : 0.f;
      float v = acc[nt][r] + b2[l * 128 + col] + resid;
      vres[r][nt] = v;
      s1 += v;
      s2 += v * v;
    }
#pragma unroll
    for (int m = 1; m < 16; m <<= 1) {
      s1 += __shfl_xor(s1, m);
      s2 += __shfl_xor(s2, m);
    }
    s1r[r] = s1; s2r[r] = s2;
  }
  __syncthreads();
  if (ln == 0) {
#pragma unroll
    for (int r = 0; r < 4; r++) {
      Ssum[cw][rw * 16 + q * 4 + r][0] = s1r[r];
      Ssum[cw][rw * 16 + q * 4 + r][1] = s2r[r];
    }
  }
  __syncthreads();
#pragma unroll
  for (int r = 0; r < 4; r++) {
    int row = rw * 16 + q * 4 + r;
    float s1 = s1r[r] + Ssum[cw ^ 1][row][0];
    float s2 = s2r[r] + Ssum[cw ^ 1][row][1];
    float mean = s1 * (1.f / 128.f);
    float rstd = rsqrtf(s2 * (1.f / 128.f) - mean * mean + 1e-5f);
    int t = t0 + row;
    if (t < L_SEQ) {
#pragma unroll
      for (int nt = 0; nt < 4; nt++) {
        int col = wcol + nt * 16 + ln;
        Hout[((size_t)b * L_SEQ + t) * 128 + col] =
            (vres[r][nt] - mean) * rstd * nw[col] + nbv[col];
      }
    }
  }
}

// ---------------------------------------------------------------------------
// k_final  (round-3, proven)
// ---------------------------------------------------------------------------
__global__ __launch_bounds__(256) void k_final(
    const float* __restrict__ Hsrc, const float* __restrict__ fw,
    const float* __restrict__ fb, const float* __restrict__ pw,
    const float* __restrict__ pb, float* __restrict__ out) {
  int b = blockIdx.y;
  int v0 = blockIdx.x * 16;
  int tid = threadIdx.x;
  __shared__ float At[128][17];
  __shared__ float Ws[32][97];
  __shared__ float Os[96][17];
  for (int i = 0; i < 8; i++) {
    int e = tid + i * 256;
    int k = e & 127, tl = e >> 7;
    At[k][tl] = Hsrc[((size_t)b * L_SEQ + v0 + tl) * 128 + k];
  }
  __syncthreads();
  {
    int g = tid & 15, tl = tid >> 4;
    float s1 = 0.f, s2 = 0.f;
#pragma unroll
    for (int kk = 0; kk < 8; kk++) {
      float v = At[g * 8 + kk][tl];
      s1 += v;
      s2 += v * v;
    }
#pragma unroll
    for (int msk = 1; msk < 16; msk <<= 1) {
      s1 += __shfl_xor(s1, msk);
      s2 += __shfl_xor(s2, msk);
    }
    float mean = s1 * (1.f / 128.f);
    float rstd = rsqrtf(s2 * (1.f / 128.f) - mean * mean + 1e-5f);
#pragma unroll
    for (int kk = 0; kk < 8; kk++) {
      int k = g * 8 + kk;
      At[k][tl] = (At[k][tl] - mean) * rstd * fw[k] + fb[k];
    }
  }
  __syncthreads();
  int tm = tid & 15, tt = tid >> 4;
  float acc[6] = {0.f};
  for (int k0 = 0; k0 < 128; k0 += 32) {
    for (int i = 0; i < 12; i++) {
      int e = tid + i * 256;
      int ki = e & 31, p = e >> 5;
      Ws[ki][p] = pw[(size_t)p * 128 + k0 + ki];
    }
    __syncthreads();
    for (int ki = 0; ki < 32; ki++) {
      float a = At[k0 + ki][tt];
#pragma unroll
      for (int jq = 0; jq < 6; jq++)
        acc[jq] = fmaf(a, Ws[ki][tm + jq * 16], acc[jq]);
    }
    __syncthreads();
  }
#pragma unroll
  for (int jq = 0; jq < 6; jq++) {
    int p = tm + jq * 16;
    Os[p][tt] = acc[jq] + pb[p];
  }
  __syncthreads();
  for (int i = 0; i < 6; i++) {
    int e = tid + i * 256;
    int vi = e & 15, p = e >> 4;
    out[((size_t)b * 96 + p) * 1024 + v0 + vi] = Os[p][vi];
  }
}

// ---------------------------------------------------------------------------
extern "C" void kernel_launch(void* const* d_in, const int* in_sizes, int n_in,
                              void* d_out, int out_size, void* d_ws, size_t ws_size,
                              hipStream_t stream) {
  (void)in_sizes; (void)n_in; (void)out_size; (void)ws_size;
  const float* x_enc  = (const float*)d_in[0];
  const float* x_mark = (const float*)d_in[1];
  const float* emb_w  = (const float*)d_in[4];
  const float* emb_b  = (const float*)d_in[5];
  const float* ipw    = (const float*)d_in[6];
  const float* cw     = (const float*)d_in[7];
  const float* cb     = (const float*)d_in[8];
  const float* xpw    = (const float*)d_in[9];
  const float* dpw    = (const float*)d_in[10];
  const float* dpb    = (const float*)d_in[11];
  const float* A_log  = (const float*)d_in[12];
  const float* Dpar   = (const float*)d_in[13];
  const float* opw    = (const float*)d_in[14];
  const float* n1w    = (const float*)d_in[15];
  const float* n1b    = (const float*)d_in[16];
  const float* n2w    = (const float*)d_in[17];
  const float* n2b    = (const float*)d_in[18];
  const float* fw1    = (const float*)d_in[19];
  const float* fb1    = (const float*)d_in[20];
  const float* fw2    = (const float*)d_in[21];
  const float* fb2    = (const float*)d_in[22];
  const float* fnw    = (const float*)d_in[23];
  const float* fnb    = (const float*)d_in[24];
  const float* pw     = (const float*)d_in[25];
  const float* pb     = (const float*)d_in[26];

  float* ws   = (float*)d_ws;
  float* H    = ws + OFF_H;
  float* H1   = ws + OFF_H1;
  float* XZ   = ws + OFF_XZ;
  float* XCT  = ws + OFF_XCT;
  float* DLT  = ws + OFF_DLT;
  float* BmT  = ws + OFF_BMT;
  float* CmT  = ws + OFF_CMT;
  float* YT   = ws + OFF_YT;
  float* sumH = ws + OFF_H1;             // overlay: H1 unused during scan

  k_embed<<<dim3(33, 8), 256, 0, stream>>>(x_enc, x_mark, emb_w, emb_b, H);
  for (int l = 0; l < 2; l++) {
    k_xz<<<dim3(33, 8, 4), 256, 0, stream>>>(H, ipw, XZ, l);
    k_mid<<<dim3(36, 8, 2), 256, 0, stream>>>(XZ, cw, cb, xpw, dpw, dpb,
                                              XCT, DLT, BmT, CmT, l);
    k_scan1<<<dim3(16, 8, 16), 256, 0, stream>>>(DLT, XCT, BmT, A_log,
                                                 sumH, YT, l);
    k_scanp<<<dim3(16, 8, 2), 64, 0, stream>>>(A_log, sumH, YT, l);
    k_scan2<<<dim3(16, 8, 16), 256, 0, stream>>>(DLT, XCT, BmT, CmT, XZ,
                                                 A_log, Dpar, sumH, YT, l);
    k_out<<<dim3(33, 8), 256, 0, stream>>>(YT, H, opw, n1w, n1b, H1, l);
    k_ffn<<<dim3(33, 8), 256, 0, stream>>>(H1, fw1, fb1, fw2, fb2, n2w, n2b, H, l);
  }
  k_final<<<dim3(64, 8), 256, 0, stream>>>(H, fnw, fnb, pw, pb, (float*)d_out);
}

// Round 11
// 389.088 us; speedup vs baseline: 1.0731x; 1.0479x over previous
//
#include <hip/hip_runtime.h>
#include <math.h>

// ---------------------------------------------------------------------------
// Bidirectional Mamba encoder, round 11.
// Round-10 structure kept (bf16-MFMA GEMMs; 3-pass chunked scan, 32 chunks
// of 36, packed 4 waves/block). ONE change: the scan stream buffers
// DLT/XCT/BmT/CmT and YT are now bf16 -> half the cache lines on the
// latency-bound scan passes. sdl stash stays fp32 (exp(A*sdl) amplifies
// rel error ~400x) in an fp32 view of YT's tail rows. YT-bf16 is free:
// k_out rounded Y to bf16 anyway before the MFMA.
// ---------------------------------------------------------------------------

#define L_SEQ 1031
#define LP    1152          // 32 chunks x 36
#define TC    36
#define NCH   32
#define SDROW 1056          // first YT tail row; rows 1056.. hold fp32 sdl
#define BATCH 8
#define NVAR  1024
#define SEQQ  512
#define TFEAT 7

// offsets in float units (buffers using bf16 occupy half their region)
#define SZ_H    ((size_t)BATCH * L_SEQ * 128)
#define SZ_XZ   ((size_t)2 * BATCH * L_SEQ * 256)
#define SZ_DT   ((size_t)2 * BATCH * 128 * LP)
#define SZ_BC   ((size_t)2 * BATCH * 16 * LP)
#define OFF_H    ((size_t)0)
#define OFF_H1   (OFF_H + SZ_H)
#define OFF_XZ   (OFF_H1 + SZ_H)
#define OFF_XCT  (OFF_XZ + SZ_XZ)
#define OFF_DLT  (OFF_XCT + SZ_DT)
#define OFF_BMT  (OFF_DLT + SZ_DT)
#define OFF_CMT  (OFF_BMT + SZ_BC)
#define OFF_YT   (OFF_CMT + SZ_BC)
#define SZ_SUM  ((size_t)2 * BATCH * NCH * 128 * 16)   // 1,048,576 <= SZ_H

typedef __bf16 bf16_t;
typedef bf16_t bf16x4 __attribute__((ext_vector_type(4)));
typedef bf16_t bf16x8 __attribute__((ext_vector_type(8)));
typedef float floatx4 __attribute__((ext_vector_type(4)));

#define MFMA16(a, b, c) __builtin_amdgcn_mfma_f32_16x16x32_bf16((a), (b), (c), 0, 0, 0)

__device__ __forceinline__ float silu_f(float x) {
  return x / (1.f + __expf(-x));
}
__device__ __forceinline__ float softplus_f(float x) {
  return (x > 20.f) ? x : log1pf(__expf(x));
}
__device__ __forceinline__ float red8(float x) {
  x += __int_as_float(__builtin_amdgcn_update_dpp(
      0, __float_as_int(x), 0xB1, 0xF, 0xF, true));   // quad_perm [1,0,3,2]
  x += __int_as_float(__builtin_amdgcn_update_dpp(
      0, __float_as_int(x), 0x4E, 0xF, 0xF, true));   // quad_perm [2,3,0,1]
  x += __int_as_float(__builtin_amdgcn_update_dpp(
      0, __float_as_int(x), 0x141, 0xF, 0xF, true));  // row_half_mirror
  return x;
}
__device__ __forceinline__ float4 b2f4(bf16x4 v) {
  return make_float4((float)v[0], (float)v[1], (float)v[2], (float)v[3]);
}
__device__ __forceinline__ bf16x4 f2b4(float a, float b, float c, float d) {
  return (bf16x4){(bf16_t)a, (bf16_t)b, (bf16_t)c, (bf16_t)d};
}

// Stage 128xK-chunk of a row-major [N][K] fp32 weight into Wbf (bf16).
#define STAGE_W128(WBUF, SRC, LDK, K0)                                       \
  _Pragma("unroll")                                                          \
  for (int i_ = 0; i_ < 16; i_++) {                                          \
    int e_ = tid + i_ * 256;                                                 \
    int n_ = e_ >> 5, kq_ = e_ & 31;                                         \
    float4 wv_ = *(const float4*)&(SRC)[(size_t)n_ * (LDK) + (K0) + kq_ * 4];\
    *(bf16x4*)&WBUF[n_][kq_ * 4] = f2b4(wv_.x, wv_.y, wv_.z, wv_.w);         \
  }

// 16 MFMAs: full K=128 panel for this wave's 16x64 output.
#define MFMA_K128(ABUF, WBUF, ACC)                                           \
  _Pragma("unroll")                                                          \
  for (int kc_ = 0; kc_ < 4; kc_++) {                                        \
    bf16x8 a_ = *(const bf16x8*)&ABUF[arow][kc_ * 32 + q8];                  \
    _Pragma("unroll")                                                        \
    for (int nt_ = 0; nt_ < 4; nt_++) {                                      \
      bf16x8 b_ = *(const bf16x8*)&WBUF[wcol + nt_ * 16 + ln][kc_ * 32 + q8];\
      ACC[nt_] = MFMA16(a_, b_, ACC[nt_]);                                   \
    }                                                                        \
  }

// ---------------------------------------------------------------------------
// k_embed  (round-8, proven)
// ---------------------------------------------------------------------------
__global__ __launch_bounds__(256) void k_embed(
    const float* __restrict__ x_enc, const float* __restrict__ x_mark,
    const float* __restrict__ emb_w, const float* __restrict__ emb_b,
    float* __restrict__ H) {
  int b = blockIdx.y;
  int v0 = blockIdx.x * 32;
  int tid = threadIdx.x;
  __shared__ bf16_t Abf[32][136];
  __shared__ bf16_t Wbf[128][136];
  int lane = tid & 63, ln = lane & 15, q = lane >> 4, q8 = q * 8;
  int w = tid >> 6, rw = w & 1, cw = w >> 1;
  int arow = rw * 16 + ln, wcol = cw * 64;
  floatx4 acc[4];
#pragma unroll
  for (int nt = 0; nt < 4; nt++) acc[nt] = (floatx4){0.f, 0.f, 0.f, 0.f};

  for (int c = 0; c < 4; c++) {
    int s0 = c * 128;
#pragma unroll
    for (int i = 0; i < 4; i++) {
      int e = tid + i * 256;
      int s = e >> 3, vq = e & 7;
      int vg = v0 + vq * 4;
      float4 xv;
      if (vg + 3 < NVAR) {
        xv = *(const float4*)&x_enc[((size_t)b * SEQQ + s0 + s) * NVAR + vg];
        if (xv.x == -9999.f) xv.x = -1.f;
        if (xv.y == -9999.f) xv.y = -1.f;
        if (xv.z == -9999.f) xv.z = -1.f;
        if (xv.w == -9999.f) xv.w = -1.f;
      } else {
        float tmp[4];
#pragma unroll
        for (int u = 0; u < 4; u++) {
          int v = vg + u;
          tmp[u] = (v < L_SEQ)
                       ? x_mark[((size_t)b * SEQQ + s0 + s) * TFEAT + (v - NVAR)]
                       : 0.f;
        }
        xv = make_float4(tmp[0], tmp[1], tmp[2], tmp[3]);
      }
      Abf[vq * 4 + 0][s] = (bf16_t)xv.x;
      Abf[vq * 4 + 1][s] = (bf16_t)xv.y;
      Abf[vq * 4 + 2][s] = (bf16_t)xv.z;
      Abf[vq * 4 + 3][s] = (bf16_t)xv.w;
    }
    STAGE_W128(Wbf, emb_w, SEQQ, s0);
    __syncthreads();
    MFMA_K128(Abf, Wbf, acc);
    __syncthreads();
  }
#pragma unroll
  for (int r = 0; r < 4; r++) {
    int v = v0 + rw * 16 + q * 4 + r;
    if (v < L_SEQ) {
      float* dst = &H[((size_t)b * L_SEQ + v) * 128];
#pragma unroll
      for (int nt = 0; nt < 4; nt++) {
        int col = wcol + nt * 16 + ln;
        dst[col] = acc[nt][r] + emb_b[col];
      }
    }
  }
}

// ---------------------------------------------------------------------------
// k_xz  (round-8, proven)
// ---------------------------------------------------------------------------
__global__ __launch_bounds__(256) void k_xz(
    const float* __restrict__ H, const float* __restrict__ ipw,
    float* __restrict__ XZ, int l) {
  int b = blockIdx.y;
  int dir = blockIdx.z >> 1, nh = blockIdx.z & 1;
  int t0 = blockIdx.x * 32;
  int tid = threadIdx.x;
  __shared__ bf16_t Abf[32][136];
  __shared__ bf16_t Wbf[128][136];
  int lane = tid & 63, ln = lane & 15, q = lane >> 4, q8 = q * 8;
  int w = tid >> 6, rw = w & 1, cw = w >> 1;
  int arow = rw * 16 + ln, wcol = cw * 64;
  floatx4 acc[4];
#pragma unroll
  for (int nt = 0; nt < 4; nt++) acc[nt] = (floatx4){0.f, 0.f, 0.f, 0.f};
  const float* wbase = ipw + (size_t)(l * 2 + dir) * 256 * 128 + (size_t)nh * 128 * 128;

#pragma unroll
  for (int i = 0; i < 4; i++) {
    int e = tid + i * 256;
    int tl = e >> 5, kq = e & 31;
    int t = t0 + tl;
    float4 hv = make_float4(0.f, 0.f, 0.f, 0.f);
    if (t < L_SEQ) {
      int st = dir ? (L_SEQ - 1 - t) : t;
      hv = *(const float4*)&H[((size_t)b * L_SEQ + st) * 128 + kq * 4];
    }
    *(bf16x4*)&Abf[tl][kq * 4] = f2b4(hv.x, hv.y, hv.z, hv.w);
  }
  STAGE_W128(Wbf, wbase, 128, 0);
  __syncthreads();
  MFMA_K128(Abf, Wbf, acc);

#pragma unroll
  for (int r = 0; r < 4; r++) {
    int t = t0 + rw * 16 + q * 4 + r;
    if (t < L_SEQ) {
      float* dst = XZ + ((size_t)(dir * BATCH + b) * L_SEQ + t) * 256 + nh * 128;
#pragma unroll
      for (int nt = 0; nt < 4; nt++) dst[wcol + nt * 16 + ln] = acc[nt][r];
    }
  }
}

// ---------------------------------------------------------------------------
// k_mid: conv+silu -> xc ; dbc = xc @ xpw.T ; delta=softplus(...).
// Writes XCT/DLT/BmT/CmT as bf16.  grid (36,8,2), block 256.
// ---------------------------------------------------------------------------
__global__ __launch_bounds__(256) void k_mid(
    const float* __restrict__ XZ,
    const float* __restrict__ conv_w, const float* __restrict__ conv_b,
    const float* __restrict__ xpw,
    const float* __restrict__ dpw, const float* __restrict__ dpb,
    bf16_t* __restrict__ XCT, bf16_t* __restrict__ DLT,
    bf16_t* __restrict__ BmT, bf16_t* __restrict__ CmT, int l) {
  int b = blockIdx.y, dir = blockIdx.z;
  int t0 = blockIdx.x * 32;
  int tid = threadIdx.x;
  int pg = l * 2 + dir;
  __shared__ float xcs[32][132];
  __shared__ float xpws[40][128];
  __shared__ float dbcs[40][36];
  const float* xz = XZ + (size_t)(dir * BATCH + b) * L_SEQ * 256;

  for (int i = 0; i < 20; i++) {
    int e = tid + i * 256;
    int k = e & 127, j = e >> 7;
    xpws[j][k] = xpw[((size_t)pg * 40 + j) * 128 + k];
  }
  for (int i = 0; i < 16; i++) {
    int e = tid + i * 256;
    int d = e & 127, tl = e >> 7;
    int t = t0 + tl;
    float v = 0.f;
    if (t < L_SEQ) {
      float x1 = xz[(size_t)t * 256 + d];
      float x0 = (t > 0) ? xz[(size_t)(t - 1) * 256 + d] : 0.f;
      float c0 = conv_w[((size_t)pg * 128 + d) * 2 + 0];
      float c1 = conv_w[((size_t)pg * 128 + d) * 2 + 1];
      v = silu_f(x0 * c0 + x1 * c1 + conv_b[(size_t)pg * 128 + d]);
    }
    xcs[tl][d] = v;
  }
  __syncthreads();
  {
    int tl = tid & 31, jg = tid >> 5;
    float acc[5] = {0.f};
    const float4* xrow = (const float4*)&xcs[tl][0];
    for (int kk = 0; kk < 32; kk++) {
      float4 a = xrow[kk];
#pragma unroll
      for (int jj = 0; jj < 5; jj++) {
        float4 w = ((const float4*)&xpws[jg * 5 + jj][0])[kk];
        acc[jj] = fmaf(a.x, w.x, acc[jj]);
        acc[jj] = fmaf(a.y, w.y, acc[jj]);
        acc[jj] = fmaf(a.z, w.z, acc[jj]);
        acc[jj] = fmaf(a.w, w.w, acc[jj]);
      }
    }
#pragma unroll
    for (int jj = 0; jj < 5; jj++) dbcs[jg * 5 + jj][tl] = acc[jj];
  }
  __syncthreads();
  for (int i = 0; i < 4; i++) {
    int e = tid + i * 256;
    int tl = e & 31, r = e >> 5;
    int n = r & 15, isC = r >> 4;
    int t = t0 + tl;
    if (t < LP) {
      float v = dbcs[8 + isC * 16 + n][tl];
      bf16_t* dst = isC ? CmT : BmT;
      dst[((size_t)(dir * BATCH + b) * 16 + n) * LP + t] = (bf16_t)v;
    }
  }
  {
    int d = tid & 127, th = tid >> 7;
    float dw[8];
#pragma unroll
    for (int k = 0; k < 8; k++) dw[k] = dpw[((size_t)pg * 128 + d) * 8 + k];
    float dbv = dpb[(size_t)pg * 128 + d];
    size_t base = ((size_t)(dir * BATCH + b) * 128 + d) * LP;
    for (int tb = th * 16; tb < th * 16 + 16; tb += 4) {
      int t = t0 + tb;
      if (t < LP) {
        float dv[4], xv[4];
#pragma unroll
        for (int u = 0; u < 4; u++) {
          int tl = tb + u;
          float a = dbv;
#pragma unroll
          for (int k = 0; k < 8; k++) a = fmaf(dbcs[k][tl], dw[k], a);
          dv[u] = softplus_f(a);
          xv[u] = xcs[tl][d];
        }
        *(bf16x4*)(DLT + base + t) = f2b4(dv[0], dv[1], dv[2], dv[3]);
        *(bf16x4*)(XCT + base + t) = f2b4(xv[0], xv[1], xv[2], xv[3]);
      }
    }
  }
}

// ---------------------------------------------------------------------------
// k_scan1: per-chunk local scan from h=0 -> h_end (sumH fp32) + sum(delta)
// (fp32 view of YT tail). 4 chunk-waves per block. grid (16,8,16), blk 256.
// ---------------------------------------------------------------------------
__global__ __launch_bounds__(256) void k_scan1(
    const bf16_t* __restrict__ DLT, const bf16_t* __restrict__ XCT,
    const bf16_t* __restrict__ BmT,
    const float* __restrict__ A_log,
    float* __restrict__ sumH, bf16_t* __restrict__ YT, int l) {
  int tid = threadIdx.x;
  int wid = tid >> 6;
  int lane = tid & 63;
  int z = blockIdx.z;
  int dir = z >> 3, jg = z & 7;
  int j = jg * 4 + wid;
  int b = blockIdx.y;
  int np = lane & 7, ds = lane >> 3;
  int d = blockIdx.x * 8 + ds;
  int pg = l * 2 + dir;
  int n0 = np * 2;
  int dirb = dir * BATCH + b;
  float A0 = -__expf(A_log[((size_t)pg * 128 + d) * 16 + n0]);
  float A1 = -__expf(A_log[((size_t)pg * 128 + d) * 16 + n0 + 1]);
  size_t bd = ((size_t)dirb * 128 + d) * LP + (size_t)j * TC;
  size_t bn = ((size_t)dirb * 16 + n0) * LP + (size_t)j * TC;
  const bf16x4* dl4 = (const bf16x4*)(DLT + bd);
  const bf16x4* xc4 = (const bf16x4*)(XCT + bd);
  const bf16x4* b04 = (const bf16x4*)(BmT + bn);
  const bf16x4* b14 = (const bf16x4*)(BmT + bn + LP);
  float h0 = 0.f, h1 = 0.f, sdl = 0.f;
  const int NI = TC / 4;   // 9
  float4 cd = b2f4(dl4[0]), cx = b2f4(xc4[0]);
  float4 cb0 = b2f4(b04[0]), cb1 = b2f4(b14[0]);
#define P1STEP(DL, XC, B0, B1)                       \
  {                                                  \
    float du_ = (DL) * (XC);                         \
    h0 = fmaf(__expf((DL) * A0), h0, du_ * (B0));    \
    h1 = fmaf(__expf((DL) * A1), h1, du_ * (B1));    \
  }
  for (int i = 0; i < NI; i++) {
    float4 nd = cd, nx = cx, nb0 = cb0, nb1 = cb1;
    if (i + 1 < NI) {
      nd = b2f4(dl4[i + 1]); nx = b2f4(xc4[i + 1]);
      nb0 = b2f4(b04[i + 1]); nb1 = b2f4(b14[i + 1]);
    }
    P1STEP(cd.x, cx.x, cb0.x, cb1.x);
    P1STEP(cd.y, cx.y, cb0.y, cb1.y);
    P1STEP(cd.z, cx.z, cb0.z, cb1.z);
    P1STEP(cd.w, cx.w, cb0.w, cb1.w);
    sdl += (cd.x + cd.y) + (cd.z + cd.w);
    cd = nd; cx = nx; cb0 = nb0; cb1 = nb1;
  }
#undef P1STEP
  size_t si = (((size_t)dirb * NCH + j) * 128 + d) * 16 + n0;
  *(float2*)&sumH[si] = make_float2(h0, h1);
  if (np == 0) {
    float* sdlp = (float*)(YT + ((size_t)dirb * LP + SDROW) * 128);
    sdlp[j * 128 + d] = sdl;
  }
}

// ---------------------------------------------------------------------------
// k_scanp: exclusive-prefix walk converting sumH in place h_end -> h_init.
// One wave per (dir,b,8d). grid (16, 8, 2), block 64. 32 serial steps.
// ---------------------------------------------------------------------------
__global__ __launch_bounds__(64) void k_scanp(
    const float* __restrict__ A_log, float* __restrict__ sumH,
    const bf16_t* __restrict__ YT, int l) {
  int dir = blockIdx.z, b = blockIdx.y;
  int lane = threadIdx.x;
  int np = lane & 7, ds = lane >> 3;
  int d = blockIdx.x * 8 + ds;
  int pg = l * 2 + dir;
  int n0 = np * 2;
  int dirb = dir * BATCH + b;
  float A0 = -__expf(A_log[((size_t)pg * 128 + d) * 16 + n0]);
  float A1 = -__expf(A_log[((size_t)pg * 128 + d) * 16 + n0 + 1]);
  size_t sbase = (((size_t)dirb * NCH) * 128 + d) * 16 + n0;
  const float* sdbase = (const float*)(YT + ((size_t)dirb * LP + SDROW) * 128) + d;
  float h0 = 0.f, h1 = 0.f;
  float2 hE = *(const float2*)&sumH[sbase];
  float sdl = sdbase[0];
  for (int j = 0; j < NCH; j++) {
    float2 hEn;
    float sdln;
    if (j + 1 < NCH) {
      hEn = *(const float2*)&sumH[sbase + (size_t)(j + 1) * 2048];
      sdln = sdbase[(size_t)(j + 1) * 128];
    }
    *(float2*)&sumH[sbase + (size_t)j * 2048] = make_float2(h0, h1);
    h0 = fmaf(__expf(A0 * sdl), h0, hE.x);
    h1 = fmaf(__expf(A1 * sdl), h1, hE.y);
    hE = hEn;
    sdl = sdln;
  }
}

// ---------------------------------------------------------------------------
// k_scan2: load h_init, re-run chunk, DPP-reduce, gate silu(z), write
// bf16 Y[t][d]. 4 chunk-waves per block. grid (16, 8, 16), block 256.
// ---------------------------------------------------------------------------
__global__ __launch_bounds__(256) void k_scan2(
    const bf16_t* __restrict__ DLT, const bf16_t* __restrict__ XCT,
    const bf16_t* __restrict__ BmT, const bf16_t* __restrict__ CmT,
    const float* __restrict__ XZ,
    const float* __restrict__ A_log, const float* __restrict__ Dpar,
    const float* __restrict__ sumH,
    bf16_t* __restrict__ YT, int l) {
  int tid = threadIdx.x;
  int wid = tid >> 6;
  int lane = tid & 63;
  int z = blockIdx.z;
  int dir = z >> 3, jg = z & 7;
  int j = jg * 4 + wid;
  int b = blockIdx.y;
  int np = lane & 7, ds = lane >> 3;
  int d = blockIdx.x * 8 + ds;
  int pg = l * 2 + dir;
  int n0 = np * 2;
  int dirb = dir * BATCH + b;
  float A0 = -__expf(A_log[((size_t)pg * 128 + d) * 16 + n0]);
  float A1 = -__expf(A_log[((size_t)pg * 128 + d) * 16 + n0 + 1]);
  float Dv = Dpar[(size_t)pg * 128 + d];
  float2 hi = *(const float2*)&sumH[(((size_t)dirb * NCH + j) * 128 + d) * 16 + n0];
  float h0 = hi.x, h1 = hi.y;
  size_t bd = ((size_t)dirb * 128 + d) * LP + (size_t)j * TC;
  size_t bn = ((size_t)dirb * 16 + n0) * LP + (size_t)j * TC;
  const bf16x4* dl4 = (const bf16x4*)(DLT + bd);
  const bf16x4* xc4 = (const bf16x4*)(XCT + bd);
  const bf16x4* b04 = (const bf16x4*)(BmT + bn);
  const bf16x4* b14 = (const bf16x4*)(BmT + bn + LP);
  const bf16x4* c04 = (const bf16x4*)(CmT + bn);
  const bf16x4* c14 = (const bf16x4*)(CmT + bn + LP);
  const float* zbase = XZ + (size_t)dirb * L_SEQ * 256 + 128 + d
                       + (size_t)j * TC * 256;
  bf16_t* ybase = YT + ((size_t)dirb * LP + (size_t)j * TC) * 128 + d;
  const int NI = TC / 4;   // 9
  float4 cd = b2f4(dl4[0]), cx = b2f4(xc4[0]);
  float4 cb0 = b2f4(b04[0]), cb1 = b2f4(b14[0]);
  float4 cc0 = b2f4(c04[0]), cc1 = b2f4(c14[0]);
  float zc[4], zn[4];
  if (np == 0) {
#pragma unroll
    for (int u = 0; u < 4; u++) zc[u] = zbase[(size_t)u * 256];
  }
#define STEP1(DL, XC, B0, B1, C0, C1, YO)            \
  {                                                  \
    float du_ = (DL) * (XC);                         \
    h0 = fmaf(__expf((DL) * A0), h0, du_ * (B0));    \
    h1 = fmaf(__expf((DL) * A1), h1, du_ * (B1));    \
    float p_ = red8(fmaf(h1, (C1), h0 * (C0)));      \
    (YO) = fmaf(Dv, (XC), p_);                       \
  }
  for (int i = 0; i < NI; i++) {
    float4 nd = cd, nx = cx, nb0 = cb0, nb1 = cb1, nc0 = cc0, nc1 = cc1;
    if (i + 1 < NI) {
      nd = b2f4(dl4[i + 1]); nx = b2f4(xc4[i + 1]);
      nb0 = b2f4(b04[i + 1]); nb1 = b2f4(b14[i + 1]);
      nc0 = b2f4(c04[i + 1]); nc1 = b2f4(c14[i + 1]);
      if (np == 0) {
        int tb = (i + 1) * 4;
#pragma unroll
        for (int u = 0; u < 4; u++) zn[u] = zbase[(size_t)(tb + u) * 256];
      }
    }
    float4 y;
    STEP1(cd.x, cx.x, cb0.x, cb1.x, cc0.x, cc1.x, y.x);
    STEP1(cd.y, cx.y, cb0.y, cb1.y, cc0.y, cc1.y, y.y);
    STEP1(cd.z, cx.z, cb0.z, cb1.z, cc0.z, cc1.z, y.z);
    STEP1(cd.w, cx.w, cb0.w, cb1.w, cc0.w, cc1.w, y.w);
    if (np == 0) {
      int tg = j * TC + i * 4;
      float yv[4] = {y.x * silu_f(zc[0]), y.y * silu_f(zc[1]),
                     y.z * silu_f(zc[2]), y.w * silu_f(zc[3])};
#pragma unroll
      for (int u = 0; u < 4; u++) {
        if (tg + u < SDROW) ybase[(size_t)(i * 4 + u) * 128] = (bf16_t)yv[u];
      }
#pragma unroll
      for (int u = 0; u < 4; u++) zc[u] = zn[u];
    }
    cd = nd; cx = nx; cb0 = nb0; cb1 = nb1; cc0 = nc0; cc1 = nc1;
  }
#undef STEP1
}

// ---------------------------------------------------------------------------
// k_out: H1 = LN1( H + Yf@opw_f.T + Yr@opw_r.T ). Y already bf16 -> direct
// LDS staging, no conversion. grid (33, 8), block 256.
// ---------------------------------------------------------------------------
__global__ __launch_bounds__(256) void k_out(
    const bf16_t* __restrict__ YT, const float* __restrict__ Hin,
    const float* __restrict__ opw,
    const float* __restrict__ n1w, const float* __restrict__ n1b,
    float* __restrict__ H1, int l) {
  int b = blockIdx.y;
  int t0 = blockIdx.x * 32;
  int tid = threadIdx.x;
  __shared__ bf16_t Abf[32][136];
  __shared__ bf16_t Wbf[128][136];
  __shared__ float Ssum[2][32][2];
  int lane = tid & 63, ln = lane & 15, q = lane >> 4, q8 = q * 8;
  int w = tid >> 6, rw = w & 1, cw = w >> 1;
  int arow = rw * 16 + ln, wcol = cw * 64;
  floatx4 acc[4];
#pragma unroll
  for (int nt = 0; nt < 4; nt++) acc[nt] = (floatx4){0.f, 0.f, 0.f, 0.f};

  for (int dirp = 0; dirp < 2; dirp++) {
    const bf16_t* ysrc = YT + (size_t)(dirp * BATCH + b) * LP * 128;
#pragma unroll
    for (int i = 0; i < 4; i++) {
      int e = tid + i * 256;
      int tl = e >> 5, dq = e & 31;
      int tg = t0 + tl;
      int srow = dirp ? (L_SEQ - 1 - tg) : tg;
      bf16x4 yv = (bf16x4){(bf16_t)0.f, (bf16_t)0.f, (bf16_t)0.f, (bf16_t)0.f};
      if (srow >= 0) yv = *(const bf16x4*)&ysrc[(size_t)srow * 128 + dq * 4];
      *(bf16x4*)&Abf[tl][dq * 4] = yv;
    }
    const float* wsrc = opw + (size_t)(l * 2 + dirp) * 128 * 128;
    STAGE_W128(Wbf, wsrc, 128, 0);
    __syncthreads();
    MFMA_K128(Abf, Wbf, acc);
    __syncthreads();
  }
  const float* nw = n1w + l * 128;
  const float* nbv = n1b + l * 128;
  float vres[4][4];
  float s1r[4], s2r[4];
#pragma unroll
  for (int r = 0; r < 4; r++) {
    int t = t0 + rw * 16 + q * 4 + r;
    float s1 = 0.f, s2 = 0.f;
#pragma unroll
    for (int nt = 0; nt < 4; nt++) {
      int col = wcol + nt * 16 + ln;
      float resid = (t < L_SEQ) ? Hin[((size_t)b * L_SEQ + t) * 128 + col] : 0.f;
      float v = acc[nt][r] + resid;
      vres[r][nt] = v;
      s1 += v;
      s2 += v * v;
    }
#pragma unroll
    for (int m = 1; m < 16; m <<= 1) {
      s1 += __shfl_xor(s1, m);
      s2 += __shfl_xor(s2, m);
    }
    s1r[r] = s1; s2r[r] = s2;
  }
  if (ln == 0) {
#pragma unroll
    for (int r = 0; r < 4; r++) {
      Ssum[cw][rw * 16 + q * 4 + r][0] = s1r[r];
      Ssum[cw][rw * 16 + q * 4 + r][1] = s2r[r];
    }
  }
  __syncthreads();
#pragma unroll
  for (int r = 0; r < 4; r++) {
    int row = rw * 16 + q * 4 + r;
    float s1 = s1r[r] + Ssum[cw ^ 1][row][0];
    float s2 = s2r[r] + Ssum[cw ^ 1][row][1];
    float mean = s1 * (1.f / 128.f);
    float rstd = rsqrtf(s2 * (1.f / 128.f) - mean * mean + 1e-5f);
    int t = t0 + row;
    if (t < L_SEQ) {
#pragma unroll
      for (int nt = 0; nt < 4; nt++) {
        int col = wcol + nt * 16 + ln;
        H1[((size_t)b * L_SEQ + t) * 128 + col] =
            (vres[r][nt] - mean) * rstd * nw[col] + nbv[col];
      }
    }
  }
}

// ---------------------------------------------------------------------------
// k_ffn  (round-8, proven)
// ---------------------------------------------------------------------------
__global__ __launch_bounds__(256) void k_ffn(
    const float* __restrict__ H1, const float* __restrict__ w1,
    const float* __restrict__ b1, const float* __restrict__ w2,
    const float* __restrict__ b2, const float* __restrict__ n2w,
    const float* __restrict__ n2b, float* __restrict__ Hout, int l) {
  int b = blockIdx.y;
  int t0 = blockIdx.x * 32;
  int tid = threadIdx.x;
  __shared__ bf16_t Abf[32][136];
  __shared__ bf16_t Wbf[128][136];
  __shared__ bf16_t Ut[32][136];
  __shared__ float Ssum[2][32][2];
  int lane = tid & 63, ln = lane & 15, q = lane >> 4, q8 = q * 8;
  int w = tid >> 6, rw = w & 1, cw = w >> 1;
  int arow = rw * 16 + ln, wcol = cw * 64;
  floatx4 acc[4];
#pragma unroll
  for (int nt = 0; nt < 4; nt++) acc[nt] = (floatx4){0.f, 0.f, 0.f, 0.f};
  const float* w1b = w1 + (size_t)l * 128 * 128;
  const float* w2b = w2 + (size_t)l * 128 * 128;

#pragma unroll
  for (int i = 0; i < 4; i++) {
    int e = tid + i * 256;
    int tl = e >> 5, kq = e & 31;
    int t = t0 + tl;
    float4 hv = make_float4(0.f, 0.f, 0.f, 0.f);
    if (t < L_SEQ)
      hv = *(const float4*)&H1[((size_t)b * L_SEQ + t) * 128 + kq * 4];
    *(bf16x4*)&Abf[tl][kq * 4] = f2b4(hv.x, hv.y, hv.z, hv.w);
  }
  STAGE_W128(Wbf, w1b, 128, 0);
  __syncthreads();
  MFMA_K128(Abf, Wbf, acc);
  __syncthreads();
  {
    float b1v[4];
#pragma unroll
    for (int nt = 0; nt < 4; nt++) b1v[nt] = b1[l * 128 + wcol + nt * 16 + ln];
#pragma unroll
    for (int nt = 0; nt < 4; nt++) {
#pragma unroll
      for (int r = 0; r < 4; r++) {
        Ut[rw * 16 + q * 4 + r][wcol + nt * 16 + ln] =
            (bf16_t)fmaxf(acc[nt][r] + b1v[nt], 0.f);
      }
      acc[nt] = (floatx4){0.f, 0.f, 0.f, 0.f};
    }
  }
  STAGE_W128(Wbf, w2b, 128, 0);
  __syncthreads();
  MFMA_K128(Ut, Wbf, acc);
  const float* nw = n2w + l * 128;
  const float* nbv = n2b + l * 128;
  float vres[4][4];
  float s1r[4], s2r[4];
#pragma unroll
  for (int r = 0; r < 4; r++) {
    int t = t0 + rw * 16 + q * 4 + r;
    float s1 = 0.f, s2 = 0.f;
#pragma unroll
    for (int nt = 0; nt < 4; nt++) {
      int col = wcol + nt * 16 + ln;
      float resid = (t < L_SEQ) ? H1[((size_t)b * L_SEQ + t) * 128 + col] : 0.f;
      float v = acc[nt][r] + b2[l * 128 + col] + resid;
      vres[r][nt] = v;
      s1 += v;
      s2 += v * v;
    }
#pragma unroll
    for (int m = 1; m < 16; m <<= 1) {
      s1 += __shfl_xor(s1, m);
      s2 += __shfl_xor(s2, m);
    }
    s1r[r] = s1; s2r[r] = s2;
  }
  __syncthreads();
  if (ln == 0) {
#pragma unroll
    for (int r = 0; r < 4; r++) {
      Ssum[cw][rw * 16 + q * 4 + r][0] = s1r[r];
      Ssum[cw][rw * 16 + q * 4 + r][1] = s2r[r];
    }
  }
  __syncthreads();
#pragma unroll
  for (int r = 0; r < 4; r++) {
    int row = rw * 16 + q * 4 + r;
    float s1 = s1r[r] + Ssum[cw ^ 1][row][0];
    float s2 = s2r[r] + Ssum[cw ^ 1][row][1];
    float mean = s1 * (1.f / 128.f);
    float rstd = rsqrtf(s2 * (1.f / 128.f) - mean * mean + 1e-5f);
    int t = t0 + row;
    if (t < L_SEQ) {
#pragma unroll
      for (int nt = 0; nt < 4; nt++) {
        int col = wcol + nt * 16 + ln;
        Hout[((size_t)b * L_SEQ + t) * 128 + col] =
            (vres[r][nt] - mean) * rstd * nw[col] + nbv[col];
      }
    }
  }
}

// ---------------------------------------------------------------------------
// k_final  (round-3, proven)
// ---------------------------------------------------------------------------
__global__ __launch_bounds__(256) void k_final(
    const float* __restrict__ Hsrc, const float* __restrict__ fw,
    const float* __restrict__ fb, const float* __restrict__ pw,
    const float* __restrict__ pb, float* __restrict__ out) {
  int b = blockIdx.y;
  int v0 = blockIdx.x * 16;
  int tid = threadIdx.x;
  __shared__ float At[128][17];
  __shared__ float Ws[32][97];
  __shared__ float Os[96][17];
  for (int i = 0; i < 8; i++) {
    int e = tid + i * 256;
    int k = e & 127, tl = e >> 7;
    At[k][tl] = Hsrc[((size_t)b * L_SEQ + v0 + tl) * 128 + k];
  }
  __syncthreads();
  {
    int g = tid & 15, tl = tid >> 4;
    float s1 = 0.f, s2 = 0.f;
#pragma unroll
    for (int kk = 0; kk < 8; kk++) {
      float v = At[g * 8 + kk][tl];
      s1 += v;
      s2 += v * v;
    }
#pragma unroll
    for (int msk = 1; msk < 16; msk <<= 1) {
      s1 += __shfl_xor(s1, msk);
      s2 += __shfl_xor(s2, msk);
    }
    float mean = s1 * (1.f / 128.f);
    float rstd = rsqrtf(s2 * (1.f / 128.f) - mean * mean + 1e-5f);
#pragma unroll
    for (int kk = 0; kk < 8; kk++) {
      int k = g * 8 + kk;
      At[k][tl] = (At[k][tl] - mean) * rstd * fw[k] + fb[k];
    }
  }
  __syncthreads();
  int tm = tid & 15, tt = tid >> 4;
  float acc[6] = {0.f};
  for (int k0 = 0; k0 < 128; k0 += 32) {
    for (int i = 0; i < 12; i++) {
      int e = tid + i * 256;
      int ki = e & 31, p = e >> 5;
      Ws[ki][p] = pw[(size_t)p * 128 + k0 + ki];
    }
    __syncthreads();
    for (int ki = 0; ki < 32; ki++) {
      float a = At[k0 + ki][tt];
#pragma unroll
      for (int jq = 0; jq < 6; jq++)
        acc[jq] = fmaf(a, Ws[ki][tm + jq * 16], acc[jq]);
    }
    __syncthreads();
  }
#pragma unroll
  for (int jq = 0; jq < 6; jq++) {
    int p = tm + jq * 16;
    Os[p][tt] = acc[jq] + pb[p];
  }
  __syncthreads();
  for (int i = 0; i < 6; i++) {
    int e = tid + i * 256;
    int vi = e & 15, p = e >> 4;
    out[((size_t)b * 96 + p) * 1024 + v0 + vi] = Os[p][vi];
  }
}

// ---------------------------------------------------------------------------
extern "C" void kernel_launch(void* const* d_in, const int* in_sizes, int n_in,
                              void* d_out, int out_size, void* d_ws, size_t ws_size,
                              hipStream_t stream) {
  (void)in_sizes; (void)n_in; (void)out_size; (void)ws_size;
  const float* x_enc  = (const float*)d_in[0];
  const float* x_mark = (const float*)d_in[1];
  const float* emb_w  = (const float*)d_in[4];
  const float* emb_b  = (const float*)d_in[5];
  const float* ipw    = (const float*)d_in[6];
  const float* cw     = (const float*)d_in[7];
  const float* cb     = (const float*)d_in[8];
  const float* xpw    = (const float*)d_in[9];
  const float* dpw    = (const float*)d_in[10];
  const float* dpb    = (const float*)d_in[11];
  const float* A_log  = (const float*)d_in[12];
  const float* Dpar   = (const float*)d_in[13];
  const float* opw    = (const float*)d_in[14];
  const float* n1w    = (const float*)d_in[15];
  const float* n1b    = (const float*)d_in[16];
  const float* n2w    = (const float*)d_in[17];
  const float* n2b    = (const float*)d_in[18];
  const float* fw1    = (const float*)d_in[19];
  const float* fb1    = (const float*)d_in[20];
  const float* fw2    = (const float*)d_in[21];
  const float* fb2    = (const float*)d_in[22];
  const float* fnw    = (const float*)d_in[23];
  const float* fnb    = (const float*)d_in[24];
  const float* pw     = (const float*)d_in[25];
  const float* pb     = (const float*)d_in[26];

  float* ws   = (float*)d_ws;
  float* H    = ws + OFF_H;
  float* H1   = ws + OFF_H1;
  float* XZ   = ws + OFF_XZ;
  bf16_t* XCT = (bf16_t*)(ws + OFF_XCT);
  bf16_t* DLT = (bf16_t*)(ws + OFF_DLT);
  bf16_t* BmT = (bf16_t*)(ws + OFF_BMT);
  bf16_t* CmT = (bf16_t*)(ws + OFF_CMT);
  bf16_t* YT  = (bf16_t*)(ws + OFF_YT);
  float* sumH = ws + OFF_H1;             // overlay: H1 unused during scan

  k_embed<<<dim3(33, 8), 256, 0, stream>>>(x_enc, x_mark, emb_w, emb_b, H);
  for (int l = 0; l < 2; l++) {
    k_xz<<<dim3(33, 8, 4), 256, 0, stream>>>(H, ipw, XZ, l);
    k_mid<<<dim3(36, 8, 2), 256, 0, stream>>>(XZ, cw, cb, xpw, dpw, dpb,
                                              XCT, DLT, BmT, CmT, l);
    k_scan1<<<dim3(16, 8, 16), 256, 0, stream>>>(DLT, XCT, BmT, A_log,
                                                 sumH, YT, l);
    k_scanp<<<dim3(16, 8, 2), 64, 0, stream>>>(A_log, sumH, YT, l);
    k_scan2<<<dim3(16, 8, 16), 256, 0, stream>>>(DLT, XCT, BmT, CmT, XZ,
                                                 A_log, Dpar, sumH, YT, l);
    k_out<<<dim3(33, 8), 256, 0, stream>>>(YT, H, opw, n1w, n1b, H1, l);
    k_ffn<<<dim3(33, 8), 256, 0, stream>>>(H1, fw1, fb1, fw2, fb2, n2w, n2b, H, l);
  }
  k_final<<<dim3(64, 8), 256, 0, stream>>>(H, fnw, fnb, pw, pb, (float*)d_out);
}

// Round 12
// 378.252 us; speedup vs baseline: 1.1039x; 1.0286x over previous
//
#include <hip/hip_runtime.h>
#include <math.h>

// ---------------------------------------------------------------------------
// Bidirectional Mamba encoder, round 12.
// Round-11 structure kept (bf16-MFMA GEMMs; bf16 scan streams; 3-pass
// chunked scan, 32 chunks of 36, 4 waves/block). ONE change: silu(z)
// gating moved from k_scan2 (scattered 32B-of-1KB-row loads inside the
// serial loop -> ~19MB of latency-bound fetch) to k_out's A-staging
// (coalesced 512B row reads amortized over MFMA panels). k_scan2 now
// writes ungated y.
// ---------------------------------------------------------------------------

#define L_SEQ 1031
#define LP    1152          // 32 chunks x 36
#define TC    36
#define NCH   32
#define SDROW 1056          // first YT tail row; rows 1056.. hold fp32 sdl
#define BATCH 8
#define NVAR  1024
#define SEQQ  512
#define TFEAT 7

// offsets in float units (buffers using bf16 occupy half their region)
#define SZ_H    ((size_t)BATCH * L_SEQ * 128)
#define SZ_XZ   ((size_t)2 * BATCH * L_SEQ * 256)
#define SZ_DT   ((size_t)2 * BATCH * 128 * LP)
#define SZ_BC   ((size_t)2 * BATCH * 16 * LP)
#define OFF_H    ((size_t)0)
#define OFF_H1   (OFF_H + SZ_H)
#define OFF_XZ   (OFF_H1 + SZ_H)
#define OFF_XCT  (OFF_XZ + SZ_XZ)
#define OFF_DLT  (OFF_XCT + SZ_DT)
#define OFF_BMT  (OFF_DLT + SZ_DT)
#define OFF_CMT  (OFF_BMT + SZ_BC)
#define OFF_YT   (OFF_CMT + SZ_BC)
#define SZ_SUM  ((size_t)2 * BATCH * NCH * 128 * 16)   // 1,048,576 <= SZ_H

typedef __bf16 bf16_t;
typedef bf16_t bf16x4 __attribute__((ext_vector_type(4)));
typedef bf16_t bf16x8 __attribute__((ext_vector_type(8)));
typedef float floatx4 __attribute__((ext_vector_type(4)));

#define MFMA16(a, b, c) __builtin_amdgcn_mfma_f32_16x16x32_bf16((a), (b), (c), 0, 0, 0)

__device__ __forceinline__ float silu_f(float x) {
  return x / (1.f + __expf(-x));
}
__device__ __forceinline__ float softplus_f(float x) {
  return (x > 20.f) ? x : log1pf(__expf(x));
}
__device__ __forceinline__ float red8(float x) {
  x += __int_as_float(__builtin_amdgcn_update_dpp(
      0, __float_as_int(x), 0xB1, 0xF, 0xF, true));   // quad_perm [1,0,3,2]
  x += __int_as_float(__builtin_amdgcn_update_dpp(
      0, __float_as_int(x), 0x4E, 0xF, 0xF, true));   // quad_perm [2,3,0,1]
  x += __int_as_float(__builtin_amdgcn_update_dpp(
      0, __float_as_int(x), 0x141, 0xF, 0xF, true));  // row_half_mirror
  return x;
}
__device__ __forceinline__ float4 b2f4(bf16x4 v) {
  return make_float4((float)v[0], (float)v[1], (float)v[2], (float)v[3]);
}
__device__ __forceinline__ bf16x4 f2b4(float a, float b, float c, float d) {
  return (bf16x4){(bf16_t)a, (bf16_t)b, (bf16_t)c, (bf16_t)d};
}

// Stage 128xK-chunk of a row-major [N][K] fp32 weight into Wbf (bf16).
#define STAGE_W128(WBUF, SRC, LDK, K0)                                       \
  _Pragma("unroll")                                                          \
  for (int i_ = 0; i_ < 16; i_++) {                                          \
    int e_ = tid + i_ * 256;                                                 \
    int n_ = e_ >> 5, kq_ = e_ & 31;                                         \
    float4 wv_ = *(const float4*)&(SRC)[(size_t)n_ * (LDK) + (K0) + kq_ * 4];\
    *(bf16x4*)&WBUF[n_][kq_ * 4] = f2b4(wv_.x, wv_.y, wv_.z, wv_.w);         \
  }

// 16 MFMAs: full K=128 panel for this wave's 16x64 output.
#define MFMA_K128(ABUF, WBUF, ACC)                                           \
  _Pragma("unroll")                                                          \
  for (int kc_ = 0; kc_ < 4; kc_++) {                                        \
    bf16x8 a_ = *(const bf16x8*)&ABUF[arow][kc_ * 32 + q8];                  \
    _Pragma("unroll")                                                        \
    for (int nt_ = 0; nt_ < 4; nt_++) {                                      \
      bf16x8 b_ = *(const bf16x8*)&WBUF[wcol + nt_ * 16 + ln][kc_ * 32 + q8];\
      ACC[nt_] = MFMA16(a_, b_, ACC[nt_]);                                   \
    }                                                                        \
  }

// ---------------------------------------------------------------------------
// k_embed  (round-8, proven)
// ---------------------------------------------------------------------------
__global__ __launch_bounds__(256) void k_embed(
    const float* __restrict__ x_enc, const float* __restrict__ x_mark,
    const float* __restrict__ emb_w, const float* __restrict__ emb_b,
    float* __restrict__ H) {
  int b = blockIdx.y;
  int v0 = blockIdx.x * 32;
  int tid = threadIdx.x;
  __shared__ bf16_t Abf[32][136];
  __shared__ bf16_t Wbf[128][136];
  int lane = tid & 63, ln = lane & 15, q = lane >> 4, q8 = q * 8;
  int w = tid >> 6, rw = w & 1, cw = w >> 1;
  int arow = rw * 16 + ln, wcol = cw * 64;
  floatx4 acc[4];
#pragma unroll
  for (int nt = 0; nt < 4; nt++) acc[nt] = (floatx4){0.f, 0.f, 0.f, 0.f};

  for (int c = 0; c < 4; c++) {
    int s0 = c * 128;
#pragma unroll
    for (int i = 0; i < 4; i++) {
      int e = tid + i * 256;
      int s = e >> 3, vq = e & 7;
      int vg = v0 + vq * 4;
      float4 xv;
      if (vg + 3 < NVAR) {
        xv = *(const float4*)&x_enc[((size_t)b * SEQQ + s0 + s) * NVAR + vg];
        if (xv.x == -9999.f) xv.x = -1.f;
        if (xv.y == -9999.f) xv.y = -1.f;
        if (xv.z == -9999.f) xv.z = -1.f;
        if (xv.w == -9999.f) xv.w = -1.f;
      } else {
        float tmp[4];
#pragma unroll
        for (int u = 0; u < 4; u++) {
          int v = vg + u;
          tmp[u] = (v < L_SEQ)
                       ? x_mark[((size_t)b * SEQQ + s0 + s) * TFEAT + (v - NVAR)]
                       : 0.f;
        }
        xv = make_float4(tmp[0], tmp[1], tmp[2], tmp[3]);
      }
      Abf[vq * 4 + 0][s] = (bf16_t)xv.x;
      Abf[vq * 4 + 1][s] = (bf16_t)xv.y;
      Abf[vq * 4 + 2][s] = (bf16_t)xv.z;
      Abf[vq * 4 + 3][s] = (bf16_t)xv.w;
    }
    STAGE_W128(Wbf, emb_w, SEQQ, s0);
    __syncthreads();
    MFMA_K128(Abf, Wbf, acc);
    __syncthreads();
  }
#pragma unroll
  for (int r = 0; r < 4; r++) {
    int v = v0 + rw * 16 + q * 4 + r;
    if (v < L_SEQ) {
      float* dst = &H[((size_t)b * L_SEQ + v) * 128];
#pragma unroll
      for (int nt = 0; nt < 4; nt++) {
        int col = wcol + nt * 16 + ln;
        dst[col] = acc[nt][r] + emb_b[col];
      }
    }
  }
}

// ---------------------------------------------------------------------------
// k_xz  (round-8, proven)
// ---------------------------------------------------------------------------
__global__ __launch_bounds__(256) void k_xz(
    const float* __restrict__ H, const float* __restrict__ ipw,
    float* __restrict__ XZ, int l) {
  int b = blockIdx.y;
  int dir = blockIdx.z >> 1, nh = blockIdx.z & 1;
  int t0 = blockIdx.x * 32;
  int tid = threadIdx.x;
  __shared__ bf16_t Abf[32][136];
  __shared__ bf16_t Wbf[128][136];
  int lane = tid & 63, ln = lane & 15, q = lane >> 4, q8 = q * 8;
  int w = tid >> 6, rw = w & 1, cw = w >> 1;
  int arow = rw * 16 + ln, wcol = cw * 64;
  floatx4 acc[4];
#pragma unroll
  for (int nt = 0; nt < 4; nt++) acc[nt] = (floatx4){0.f, 0.f, 0.f, 0.f};
  const float* wbase = ipw + (size_t)(l * 2 + dir) * 256 * 128 + (size_t)nh * 128 * 128;

#pragma unroll
  for (int i = 0; i < 4; i++) {
    int e = tid + i * 256;
    int tl = e >> 5, kq = e & 31;
    int t = t0 + tl;
    float4 hv = make_float4(0.f, 0.f, 0.f, 0.f);
    if (t < L_SEQ) {
      int st = dir ? (L_SEQ - 1 - t) : t;
      hv = *(const float4*)&H[((size_t)b * L_SEQ + st) * 128 + kq * 4];
    }
    *(bf16x4*)&Abf[tl][kq * 4] = f2b4(hv.x, hv.y, hv.z, hv.w);
  }
  STAGE_W128(Wbf, wbase, 128, 0);
  __syncthreads();
  MFMA_K128(Abf, Wbf, acc);

#pragma unroll
  for (int r = 0; r < 4; r++) {
    int t = t0 + rw * 16 + q * 4 + r;
    if (t < L_SEQ) {
      float* dst = XZ + ((size_t)(dir * BATCH + b) * L_SEQ + t) * 256 + nh * 128;
#pragma unroll
      for (int nt = 0; nt < 4; nt++) dst[wcol + nt * 16 + ln] = acc[nt][r];
    }
  }
}

// ---------------------------------------------------------------------------
// k_mid  (round-11, proven; bf16 stream outputs; grid (36,8,2))
// ---------------------------------------------------------------------------
__global__ __launch_bounds__(256) void k_mid(
    const float* __restrict__ XZ,
    const float* __restrict__ conv_w, const float* __restrict__ conv_b,
    const float* __restrict__ xpw,
    const float* __restrict__ dpw, const float* __restrict__ dpb,
    bf16_t* __restrict__ XCT, bf16_t* __restrict__ DLT,
    bf16_t* __restrict__ BmT, bf16_t* __restrict__ CmT, int l) {
  int b = blockIdx.y, dir = blockIdx.z;
  int t0 = blockIdx.x * 32;
  int tid = threadIdx.x;
  int pg = l * 2 + dir;
  __shared__ float xcs[32][132];
  __shared__ float xpws[40][128];
  __shared__ float dbcs[40][36];
  const float* xz = XZ + (size_t)(dir * BATCH + b) * L_SEQ * 256;

  for (int i = 0; i < 20; i++) {
    int e = tid + i * 256;
    int k = e & 127, j = e >> 7;
    xpws[j][k] = xpw[((size_t)pg * 40 + j) * 128 + k];
  }
  for (int i = 0; i < 16; i++) {
    int e = tid + i * 256;
    int d = e & 127, tl = e >> 7;
    int t = t0 + tl;
    float v = 0.f;
    if (t < L_SEQ) {
      float x1 = xz[(size_t)t * 256 + d];
      float x0 = (t > 0) ? xz[(size_t)(t - 1) * 256 + d] : 0.f;
      float c0 = conv_w[((size_t)pg * 128 + d) * 2 + 0];
      float c1 = conv_w[((size_t)pg * 128 + d) * 2 + 1];
      v = silu_f(x0 * c0 + x1 * c1 + conv_b[(size_t)pg * 128 + d]);
    }
    xcs[tl][d] = v;
  }
  __syncthreads();
  {
    int tl = tid & 31, jg = tid >> 5;
    float acc[5] = {0.f};
    const float4* xrow = (const float4*)&xcs[tl][0];
    for (int kk = 0; kk < 32; kk++) {
      float4 a = xrow[kk];
#pragma unroll
      for (int jj = 0; jj < 5; jj++) {
        float4 w = ((const float4*)&xpws[jg * 5 + jj][0])[kk];
        acc[jj] = fmaf(a.x, w.x, acc[jj]);
        acc[jj] = fmaf(a.y, w.y, acc[jj]);
        acc[jj] = fmaf(a.z, w.z, acc[jj]);
        acc[jj] = fmaf(a.w, w.w, acc[jj]);
      }
    }
#pragma unroll
    for (int jj = 0; jj < 5; jj++) dbcs[jg * 5 + jj][tl] = acc[jj];
  }
  __syncthreads();
  for (int i = 0; i < 4; i++) {
    int e = tid + i * 256;
    int tl = e & 31, r = e >> 5;
    int n = r & 15, isC = r >> 4;
    int t = t0 + tl;
    if (t < LP) {
      float v = dbcs[8 + isC * 16 + n][tl];
      bf16_t* dst = isC ? CmT : BmT;
      dst[((size_t)(dir * BATCH + b) * 16 + n) * LP + t] = (bf16_t)v;
    }
  }
  {
    int d = tid & 127, th = tid >> 7;
    float dw[8];
#pragma unroll
    for (int k = 0; k < 8; k++) dw[k] = dpw[((size_t)pg * 128 + d) * 8 + k];
    float dbv = dpb[(size_t)pg * 128 + d];
    size_t base = ((size_t)(dir * BATCH + b) * 128 + d) * LP;
    for (int tb = th * 16; tb < th * 16 + 16; tb += 4) {
      int t = t0 + tb;
      if (t < LP) {
        float dv[4], xv[4];
#pragma unroll
        for (int u = 0; u < 4; u++) {
          int tl = tb + u;
          float a = dbv;
#pragma unroll
          for (int k = 0; k < 8; k++) a = fmaf(dbcs[k][tl], dw[k], a);
          dv[u] = softplus_f(a);
          xv[u] = xcs[tl][d];
        }
        *(bf16x4*)(DLT + base + t) = f2b4(dv[0], dv[1], dv[2], dv[3]);
        *(bf16x4*)(XCT + base + t) = f2b4(xv[0], xv[1], xv[2], xv[3]);
      }
    }
  }
}

// ---------------------------------------------------------------------------
// k_scan1  (round-11, proven)
// ---------------------------------------------------------------------------
__global__ __launch_bounds__(256) void k_scan1(
    const bf16_t* __restrict__ DLT, const bf16_t* __restrict__ XCT,
    const bf16_t* __restrict__ BmT,
    const float* __restrict__ A_log,
    float* __restrict__ sumH, bf16_t* __restrict__ YT, int l) {
  int tid = threadIdx.x;
  int wid = tid >> 6;
  int lane = tid & 63;
  int z = blockIdx.z;
  int dir = z >> 3, jg = z & 7;
  int j = jg * 4 + wid;
  int b = blockIdx.y;
  int np = lane & 7, ds = lane >> 3;
  int d = blockIdx.x * 8 + ds;
  int pg = l * 2 + dir;
  int n0 = np * 2;
  int dirb = dir * BATCH + b;
  float A0 = -__expf(A_log[((size_t)pg * 128 + d) * 16 + n0]);
  float A1 = -__expf(A_log[((size_t)pg * 128 + d) * 16 + n0 + 1]);
  size_t bd = ((size_t)dirb * 128 + d) * LP + (size_t)j * TC;
  size_t bn = ((size_t)dirb * 16 + n0) * LP + (size_t)j * TC;
  const bf16x4* dl4 = (const bf16x4*)(DLT + bd);
  const bf16x4* xc4 = (const bf16x4*)(XCT + bd);
  const bf16x4* b04 = (const bf16x4*)(BmT + bn);
  const bf16x4* b14 = (const bf16x4*)(BmT + bn + LP);
  float h0 = 0.f, h1 = 0.f, sdl = 0.f;
  const int NI = TC / 4;   // 9
  float4 cd = b2f4(dl4[0]), cx = b2f4(xc4[0]);
  float4 cb0 = b2f4(b04[0]), cb1 = b2f4(b14[0]);
#define P1STEP(DL, XC, B0, B1)                       \
  {                                                  \
    float du_ = (DL) * (XC);                         \
    h0 = fmaf(__expf((DL) * A0), h0, du_ * (B0));    \
    h1 = fmaf(__expf((DL) * A1), h1, du_ * (B1));    \
  }
  for (int i = 0; i < NI; i++) {
    float4 nd = cd, nx = cx, nb0 = cb0, nb1 = cb1;
    if (i + 1 < NI) {
      nd = b2f4(dl4[i + 1]); nx = b2f4(xc4[i + 1]);
      nb0 = b2f4(b04[i + 1]); nb1 = b2f4(b14[i + 1]);
    }
    P1STEP(cd.x, cx.x, cb0.x, cb1.x);
    P1STEP(cd.y, cx.y, cb0.y, cb1.y);
    P1STEP(cd.z, cx.z, cb0.z, cb1.z);
    P1STEP(cd.w, cx.w, cb0.w, cb1.w);
    sdl += (cd.x + cd.y) + (cd.z + cd.w);
    cd = nd; cx = nx; cb0 = nb0; cb1 = nb1;
  }
#undef P1STEP
  size_t si = (((size_t)dirb * NCH + j) * 128 + d) * 16 + n0;
  *(float2*)&sumH[si] = make_float2(h0, h1);
  if (np == 0) {
    float* sdlp = (float*)(YT + ((size_t)dirb * LP + SDROW) * 128);
    sdlp[j * 128 + d] = sdl;
  }
}

// ---------------------------------------------------------------------------
// k_scanp  (round-11, proven)
// ---------------------------------------------------------------------------
__global__ __launch_bounds__(64) void k_scanp(
    const float* __restrict__ A_log, float* __restrict__ sumH,
    const bf16_t* __restrict__ YT, int l) {
  int dir = blockIdx.z, b = blockIdx.y;
  int lane = threadIdx.x;
  int np = lane & 7, ds = lane >> 3;
  int d = blockIdx.x * 8 + ds;
  int pg = l * 2 + dir;
  int n0 = np * 2;
  int dirb = dir * BATCH + b;
  float A0 = -__expf(A_log[((size_t)pg * 128 + d) * 16 + n0]);
  float A1 = -__expf(A_log[((size_t)pg * 128 + d) * 16 + n0 + 1]);
  size_t sbase = (((size_t)dirb * NCH) * 128 + d) * 16 + n0;
  const float* sdbase = (const float*)(YT + ((size_t)dirb * LP + SDROW) * 128) + d;
  float h0 = 0.f, h1 = 0.f;
  float2 hE = *(const float2*)&sumH[sbase];
  float sdl = sdbase[0];
  for (int j = 0; j < NCH; j++) {
    float2 hEn;
    float sdln;
    if (j + 1 < NCH) {
      hEn = *(const float2*)&sumH[sbase + (size_t)(j + 1) * 2048];
      sdln = sdbase[(size_t)(j + 1) * 128];
    }
    *(float2*)&sumH[sbase + (size_t)j * 2048] = make_float2(h0, h1);
    h0 = fmaf(__expf(A0 * sdl), h0, hE.x);
    h1 = fmaf(__expf(A1 * sdl), h1, hE.y);
    hE = hEn;
    sdl = sdln;
  }
}

// ---------------------------------------------------------------------------
// k_scan2: load h_init, re-run chunk, DPP-reduce, write UNGATED bf16
// Y[t][d] (gating moved to k_out). grid (16, 8, 16), block 256.
// ---------------------------------------------------------------------------
__global__ __launch_bounds__(256) void k_scan2(
    const bf16_t* __restrict__ DLT, const bf16_t* __restrict__ XCT,
    const bf16_t* __restrict__ BmT, const bf16_t* __restrict__ CmT,
    const float* __restrict__ A_log, const float* __restrict__ Dpar,
    const float* __restrict__ sumH,
    bf16_t* __restrict__ YT, int l) {
  int tid = threadIdx.x;
  int wid = tid >> 6;
  int lane = tid & 63;
  int z = blockIdx.z;
  int dir = z >> 3, jg = z & 7;
  int j = jg * 4 + wid;
  int b = blockIdx.y;
  int np = lane & 7, ds = lane >> 3;
  int d = blockIdx.x * 8 + ds;
  int pg = l * 2 + dir;
  int n0 = np * 2;
  int dirb = dir * BATCH + b;
  float A0 = -__expf(A_log[((size_t)pg * 128 + d) * 16 + n0]);
  float A1 = -__expf(A_log[((size_t)pg * 128 + d) * 16 + n0 + 1]);
  float Dv = Dpar[(size_t)pg * 128 + d];
  float2 hi = *(const float2*)&sumH[(((size_t)dirb * NCH + j) * 128 + d) * 16 + n0];
  float h0 = hi.x, h1 = hi.y;
  size_t bd = ((size_t)dirb * 128 + d) * LP + (size_t)j * TC;
  size_t bn = ((size_t)dirb * 16 + n0) * LP + (size_t)j * TC;
  const bf16x4* dl4 = (const bf16x4*)(DLT + bd);
  const bf16x4* xc4 = (const bf16x4*)(XCT + bd);
  const bf16x4* b04 = (const bf16x4*)(BmT + bn);
  const bf16x4* b14 = (const bf16x4*)(BmT + bn + LP);
  const bf16x4* c04 = (const bf16x4*)(CmT + bn);
  const bf16x4* c14 = (const bf16x4*)(CmT + bn + LP);
  bf16_t* ybase = YT + ((size_t)dirb * LP + (size_t)j * TC) * 128 + d;
  const int NI = TC / 4;   // 9
  float4 cd = b2f4(dl4[0]), cx = b2f4(xc4[0]);
  float4 cb0 = b2f4(b04[0]), cb1 = b2f4(b14[0]);
  float4 cc0 = b2f4(c04[0]), cc1 = b2f4(c14[0]);
#define STEP1(DL, XC, B0, B1, C0, C1, YO)            \
  {                                                  \
    float du_ = (DL) * (XC);                         \
    h0 = fmaf(__expf((DL) * A0), h0, du_ * (B0));    \
    h1 = fmaf(__expf((DL) * A1), h1, du_ * (B1));    \
    float p_ = red8(fmaf(h1, (C1), h0 * (C0)));      \
    (YO) = fmaf(Dv, (XC), p_);                       \
  }
  for (int i = 0; i < NI; i++) {
    float4 nd = cd, nx = cx, nb0 = cb0, nb1 = cb1, nc0 = cc0, nc1 = cc1;
    if (i + 1 < NI) {
      nd = b2f4(dl4[i + 1]); nx = b2f4(xc4[i + 1]);
      nb0 = b2f4(b04[i + 1]); nb1 = b2f4(b14[i + 1]);
      nc0 = b2f4(c04[i + 1]); nc1 = b2f4(c14[i + 1]);
    }
    float4 y;
    STEP1(cd.x, cx.x, cb0.x, cb1.x, cc0.x, cc1.x, y.x);
    STEP1(cd.y, cx.y, cb0.y, cb1.y, cc0.y, cc1.y, y.y);
    STEP1(cd.z, cx.z, cb0.z, cb1.z, cc0.z, cc1.z, y.z);
    STEP1(cd.w, cx.w, cb0.w, cb1.w, cc0.w, cc1.w, y.w);
    if (np == 0) {
      int tg = j * TC + i * 4;
#pragma unroll
      for (int u = 0; u < 4; u++) {
        float yv = (u == 0) ? y.x : (u == 1) ? y.y : (u == 2) ? y.z : y.w;
        if (tg + u < SDROW) ybase[(size_t)(i * 4 + u) * 128] = (bf16_t)yv;
      }
    }
    cd = nd; cx = nx; cb0 = nb0; cb1 = nb1; cc0 = nc0; cc1 = nc1;
  }
#undef STEP1
}

// ---------------------------------------------------------------------------
// k_out: H1 = LN1( H + (Yf*silu(zf))@opw_f.T + (Yr*silu(zr))@opw_r.T ).
// Gating applied during coalesced A-staging (z row = same srow as Y row).
// grid (33, 8), block 256.
// ---------------------------------------------------------------------------
__global__ __launch_bounds__(256) void k_out(
    const bf16_t* __restrict__ YT, const float* __restrict__ XZ,
    const float* __restrict__ Hin,
    const float* __restrict__ opw,
    const float* __restrict__ n1w, const float* __restrict__ n1b,
    float* __restrict__ H1, int l) {
  int b = blockIdx.y;
  int t0 = blockIdx.x * 32;
  int tid = threadIdx.x;
  __shared__ bf16_t Abf[32][136];
  __shared__ bf16_t Wbf[128][136];
  __shared__ float Ssum[2][32][2];
  int lane = tid & 63, ln = lane & 15, q = lane >> 4, q8 = q * 8;
  int w = tid >> 6, rw = w & 1, cw = w >> 1;
  int arow = rw * 16 + ln, wcol = cw * 64;
  floatx4 acc[4];
#pragma unroll
  for (int nt = 0; nt < 4; nt++) acc[nt] = (floatx4){0.f, 0.f, 0.f, 0.f};

  for (int dirp = 0; dirp < 2; dirp++) {
    const bf16_t* ysrc = YT + (size_t)(dirp * BATCH + b) * LP * 128;
    const float* zsrc = XZ + (size_t)(dirp * BATCH + b) * L_SEQ * 256 + 128;
#pragma unroll
    for (int i = 0; i < 4; i++) {
      int e = tid + i * 256;
      int tl = e >> 5, dq = e & 31;
      int tg = t0 + tl;
      int srow = dirp ? (L_SEQ - 1 - tg) : tg;
      bf16x4 out = (bf16x4){(bf16_t)0.f, (bf16_t)0.f, (bf16_t)0.f, (bf16_t)0.f};
      if (srow >= 0 && srow < L_SEQ) {
        float4 yv = b2f4(*(const bf16x4*)&ysrc[(size_t)srow * 128 + dq * 4]);
        float4 zv = *(const float4*)&zsrc[(size_t)srow * 256 + dq * 4];
        out = f2b4(yv.x * silu_f(zv.x), yv.y * silu_f(zv.y),
                   yv.z * silu_f(zv.z), yv.w * silu_f(zv.w));
      }
      *(bf16x4*)&Abf[tl][dq * 4] = out;
    }
    const float* wsrc = opw + (size_t)(l * 2 + dirp) * 128 * 128;
    STAGE_W128(Wbf, wsrc, 128, 0);
    __syncthreads();
    MFMA_K128(Abf, Wbf, acc);
    __syncthreads();
  }
  const float* nw = n1w + l * 128;
  const float* nbv = n1b + l * 128;
  float vres[4][4];
  float s1r[4], s2r[4];
#pragma unroll
  for (int r = 0; r < 4; r++) {
    int t = t0 + rw * 16 + q * 4 + r;
    float s1 = 0.f, s2 = 0.f;
#pragma unroll
    for (int nt = 0; nt < 4; nt++) {
      int col = wcol + nt * 16 + ln;
      float resid = (t < L_SEQ) ? Hin[((size_t)b * L_SEQ + t) * 128 + col] : 0.f;
      float v = acc[nt][r] + resid;
      vres[r][nt] = v;
      s1 += v;
      s2 += v * v;
    }
#pragma unroll
    for (int m = 1; m < 16; m <<= 1) {
      s1 += __shfl_xor(s1, m);
      s2 += __shfl_xor(s2, m);
    }
    s1r[r] = s1; s2r[r] = s2;
  }
  if (ln == 0) {
#pragma unroll
    for (int r = 0; r < 4; r++) {
      Ssum[cw][rw * 16 + q * 4 + r][0] = s1r[r];
      Ssum[cw][rw * 16 + q * 4 + r][1] = s2r[r];
    }
  }
  __syncthreads();
#pragma unroll
  for (int r = 0; r < 4; r++) {
    int row = rw * 16 + q * 4 + r;
    float s1 = s1r[r] + Ssum[cw ^ 1][row][0];
    float s2 = s2r[r] + Ssum[cw ^ 1][row][1];
    float mean = s1 * (1.f / 128.f);
    float rstd = rsqrtf(s2 * (1.f / 128.f) - mean * mean + 1e-5f);
    int t = t0 + row;
    if (t < L_SEQ) {
#pragma unroll
      for (int nt = 0; nt < 4; nt++) {
        int col = wcol + nt * 16 + ln;
        H1[((size_t)b * L_SEQ + t) * 128 + col] =
            (vres[r][nt] - mean) * rstd * nw[col] + nbv[col];
      }
    }
  }
}

// ---------------------------------------------------------------------------
// k_ffn  (round-8, proven)
// ---------------------------------------------------------------------------
__global__ __launch_bounds__(256) void k_ffn(
    const float* __restrict__ H1, const float* __restrict__ w1,
    const float* __restrict__ b1, const float* __restrict__ w2,
    const float* __restrict__ b2, const float* __restrict__ n2w,
    const float* __restrict__ n2b, float* __restrict__ Hout, int l) {
  int b = blockIdx.y;
  int t0 = blockIdx.x * 32;
  int tid = threadIdx.x;
  __shared__ bf16_t Abf[32][136];
  __shared__ bf16_t Wbf[128][136];
  __shared__ bf16_t Ut[32][136];
  __shared__ float Ssum[2][32][2];
  int lane = tid & 63, ln = lane & 15, q = lane >> 4, q8 = q * 8;
  int w = tid >> 6, rw = w & 1, cw = w >> 1;
  int arow = rw * 16 + ln, wcol = cw * 64;
  floatx4 acc[4];
#pragma unroll
  for (int nt = 0; nt < 4; nt++) acc[nt] = (floatx4){0.f, 0.f, 0.f, 0.f};
  const float* w1b = w1 + (size_t)l * 128 * 128;
  const float* w2b = w2 + (size_t)l * 128 * 128;

#pragma unroll
  for (int i = 0; i < 4; i++) {
    int e = tid + i * 256;
    int tl = e >> 5, kq = e & 31;
    int t = t0 + tl;
    float4 hv = make_float4(0.f, 0.f, 0.f, 0.f);
    if (t < L_SEQ)
      hv = *(const float4*)&H1[((size_t)b * L_SEQ + t) * 128 + kq * 4];
    *(bf16x4*)&Abf[tl][kq * 4] = f2b4(hv.x, hv.y, hv.z, hv.w);
  }
  STAGE_W128(Wbf, w1b, 128, 0);
  __syncthreads();
  MFMA_K128(Abf, Wbf, acc);
  __syncthreads();
  {
    float b1v[4];
#pragma unroll
    for (int nt = 0; nt < 4; nt++) b1v[nt] = b1[l * 128 + wcol + nt * 16 + ln];
#pragma unroll
    for (int nt = 0; nt < 4; nt++) {
#pragma unroll
      for (int r = 0; r < 4; r++) {
        Ut[rw * 16 + q * 4 + r][wcol + nt * 16 + ln] =
            (bf16_t)fmaxf(acc[nt][r] + b1v[nt], 0.f);
      }
      acc[nt] = (floatx4){0.f, 0.f, 0.f, 0.f};
    }
  }
  STAGE_W128(Wbf, w2b, 128, 0);
  __syncthreads();
  MFMA_K128(Ut, Wbf, acc);
  const float* nw = n2w + l * 128;
  const float* nbv = n2b + l * 128;
  float vres[4][4];
  float s1r[4], s2r[4];
#pragma unroll
  for (int r = 0; r < 4; r++) {
    int t = t0 + rw * 16 + q * 4 + r;
    float s1 = 0.f, s2 = 0.f;
#pragma unroll
    for (int nt = 0; nt < 4; nt++) {
      int col = wcol + nt * 16 + ln;
      float resid = (t < L_SEQ) ? H1[((size_t)b * L_SEQ + t) * 128 + col] : 0.f;
      float v = acc[nt][r] + b2[l * 128 + col] + resid;
      vres[r][nt] = v;
      s1 += v;
      s2 += v * v;
    }
#pragma unroll
    for (int m = 1; m < 16; m <<= 1) {
      s1 += __shfl_xor(s1, m);
      s2 += __shfl_xor(s2, m);
    }
    s1r[r] = s1; s2r[r] = s2;
  }
  __syncthreads();
  if (ln == 0) {
#pragma unroll
    for (int r = 0; r < 4; r++) {
      Ssum[cw][rw * 16 + q * 4 + r][0] = s1r[r];
      Ssum[cw][rw * 16 + q * 4 + r][1] = s2r[r];
    }
  }
  __syncthreads();
#pragma unroll
  for (int r = 0; r < 4; r++) {
    int row = rw * 16 + q * 4 + r;
    float s1 = s1r[r] + Ssum[cw ^ 1][row][0];
    float s2 = s2r[r] + Ssum[cw ^ 1][row][1];
    float mean = s1 * (1.f / 128.f);
    float rstd = rsqrtf(s2 * (1.f / 128.f) - mean * mean + 1e-5f);
    int t = t0 + row;
    if (t < L_SEQ) {
#pragma unroll
      for (int nt = 0; nt < 4; nt++) {
        int col = wcol + nt * 16 + ln;
        Hout[((size_t)b * L_SEQ + t) * 128 + col] =
            (vres[r][nt] - mean) * rstd * nw[col] + nbv[col];
      }
    }
  }
}

// ---------------------------------------------------------------------------
// k_final  (round-3, proven)
// ---------------------------------------------------------------------------
__global__ __launch_bounds__(256) void k_final(
    const float* __restrict__ Hsrc, const float* __restrict__ fw,
    const float* __restrict__ fb, const float* __restrict__ pw,
    const float* __restrict__ pb, float* __restrict__ out) {
  int b = blockIdx.y;
  int v0 = blockIdx.x * 16;
  int tid = threadIdx.x;
  __shared__ float At[128][17];
  __shared__ float Ws[32][97];
  __shared__ float Os[96][17];
  for (int i = 0; i < 8; i++) {
    int e = tid + i * 256;
    int k = e & 127, tl = e >> 7;
    At[k][tl] = Hsrc[((size_t)b * L_SEQ + v0 + tl) * 128 + k];
  }
  __syncthreads();
  {
    int g = tid & 15, tl = tid >> 4;
    float s1 = 0.f, s2 = 0.f;
#pragma unroll
    for (int kk = 0; kk < 8; kk++) {
      float v = At[g * 8 + kk][tl];
      s1 += v;
      s2 += v * v;
    }
#pragma unroll
    for (int msk = 1; msk < 16; msk <<= 1) {
      s1 += __shfl_xor(s1, msk);
      s2 += __shfl_xor(s2, msk);
    }
    float mean = s1 * (1.f / 128.f);
    float rstd = rsqrtf(s2 * (1.f / 128.f) - mean * mean + 1e-5f);
#pragma unroll
    for (int kk = 0; kk < 8; kk++) {
      int k = g * 8 + kk;
      At[k][tl] = (At[k][tl] - mean) * rstd * fw[k] + fb[k];
    }
  }
  __syncthreads();
  int tm = tid & 15, tt = tid >> 4;
  float acc[6] = {0.f};
  for (int k0 = 0; k0 < 128; k0 += 32) {
    for (int i = 0; i < 12; i++) {
      int e = tid + i * 256;
      int ki = e & 31, p = e >> 5;
      Ws[ki][p] = pw[(size_t)p * 128 + k0 + ki];
    }
    __syncthreads();
    for (int ki = 0; ki < 32; ki++) {
      float a = At[k0 + ki][tt];
#pragma unroll
      for (int jq = 0; jq < 6; jq++)
        acc[jq] = fmaf(a, Ws[ki][tm + jq * 16], acc[jq]);
    }
    __syncthreads();
  }
#pragma unroll
  for (int jq = 0; jq < 6; jq++) {
    int p = tm + jq * 16;
    Os[p][tt] = acc[jq] + pb[p];
  }
  __syncthreads();
  for (int i = 0; i < 6; i++) {
    int e = tid + i * 256;
    int vi = e & 15, p = e >> 4;
    out[((size_t)b * 96 + p) * 1024 + v0 + vi] = Os[p][vi];
  }
}

// ---------------------------------------------------------------------------
extern "C" void kernel_launch(void* const* d_in, const int* in_sizes, int n_in,
                              void* d_out, int out_size, void* d_ws, size_t ws_size,
                              hipStream_t stream) {
  (void)in_sizes; (void)n_in; (void)out_size; (void)ws_size;
  const float* x_enc  = (const float*)d_in[0];
  const float* x_mark = (const float*)d_in[1];
  const float* emb_w  = (const float*)d_in[4];
  const float* emb_b  = (const float*)d_in[5];
  const float* ipw    = (const float*)d_in[6];
  const float* cw     = (const float*)d_in[7];
  const float* cb     = (const float*)d_in[8];
  const float* xpw    = (const float*)d_in[9];
  const float* dpw    = (const float*)d_in[10];
  const float* dpb    = (const float*)d_in[11];
  const float* A_log  = (const float*)d_in[12];
  const float* Dpar   = (const float*)d_in[13];
  const float* opw    = (const float*)d_in[14];
  const float* n1w    = (const float*)d_in[15];
  const float* n1b    = (const float*)d_in[16];
  const float* n2w    = (const float*)d_in[17];
  const float* n2b    = (const float*)d_in[18];
  const float* fw1    = (const float*)d_in[19];
  const float* fb1    = (const float*)d_in[20];
  const float* fw2    = (const float*)d_in[21];
  const float* fb2    = (const float*)d_in[22];
  const float* fnw    = (const float*)d_in[23];
  const float* fnb    = (const float*)d_in[24];
  const float* pw     = (const float*)d_in[25];
  const float* pb     = (const float*)d_in[26];

  float* ws   = (float*)d_ws;
  float* H    = ws + OFF_H;
  float* H1   = ws + OFF_H1;
  float* XZ   = ws + OFF_XZ;
  bf16_t* XCT = (bf16_t*)(ws + OFF_XCT);
  bf16_t* DLT = (bf16_t*)(ws + OFF_DLT);
  bf16_t* BmT = (bf16_t*)(ws + OFF_BMT);
  bf16_t* CmT = (bf16_t*)(ws + OFF_CMT);
  bf16_t* YT  = (bf16_t*)(ws + OFF_YT);
  float* sumH = ws + OFF_H1;             // overlay: H1 unused during scan

  k_embed<<<dim3(33, 8), 256, 0, stream>>>(x_enc, x_mark, emb_w, emb_b, H);
  for (int l = 0; l < 2; l++) {
    k_xz<<<dim3(33, 8, 4), 256, 0, stream>>>(H, ipw, XZ, l);
    k_mid<<<dim3(36, 8, 2), 256, 0, stream>>>(XZ, cw, cb, xpw, dpw, dpb,
                                              XCT, DLT, BmT, CmT, l);
    k_scan1<<<dim3(16, 8, 16), 256, 0, stream>>>(DLT, XCT, BmT, A_log,
                                                 sumH, YT, l);
    k_scanp<<<dim3(16, 8, 2), 64, 0, stream>>>(A_log, sumH, YT, l);
    k_scan2<<<dim3(16, 8, 16), 256, 0, stream>>>(DLT, XCT, BmT, CmT,
                                                 A_log, Dpar, sumH, YT, l);
    k_out<<<dim3(33, 8), 256, 0, stream>>>(YT, XZ, H, opw, n1w, n1b, H1, l);
    k_ffn<<<dim3(33, 8), 256, 0, stream>>>(H1, fw1, fb1, fw2, fb2, n2w, n2b, H, l);
  }
  k_final<<<dim3(64, 8), 256, 0, stream>>>(H, fnw, fnb, pw, pb, (float*)d_out);
}